// Round 1
// baseline (2156.356 us; speedup 1.0000x reference)
//
#include <hip/hip_runtime.h>
#include <hip/hip_bf16.h>

#define LQ 20197
#define NBATCH 2
#define MROWS (NBATCH * LQ)   // 40394

// level geometry (static per problem)
__device__ __constant__ int dummy_unused;  // keep nothing weird

__device__ __forceinline__ float toF(float v) { return v; }
__device__ __forceinline__ float toF(__hip_bfloat16 v) { return __bfloat162float(v); }

__device__ __forceinline__ void loadA4(const float* p, float o[4]) {
    float4 v = *(const float4*)p;
    o[0] = v.x; o[1] = v.y; o[2] = v.z; o[3] = v.w;
}
__device__ __forceinline__ void loadA4(const __hip_bfloat16* p, float o[4]) {
    ushort4 u = *(const ushort4*)p;
    __hip_bfloat16 b;
    unsigned short* bs = (unsigned short*)&b;
    *bs = u.x; o[0] = __bfloat162float(b);
    *bs = u.y; o[1] = __bfloat162float(b);
    *bs = u.z; o[2] = __bfloat162float(b);
    *bs = u.w; o[3] = __bfloat162float(b);
}

__device__ __forceinline__ void storeC(float* p, float v) { *p = v; }
__device__ __forceinline__ void storeC(__hip_bfloat16* p, float v) { *p = __float2bfloat16(v); }

// ---------------- generic tiled GEMM: C = A(MxK) @ B(KxN) + bias ----------------
// BM=64, BN=64, BK=32, 256 threads, 4x4 microtile.
template<typename TOUT, bool RELU>
__global__ __launch_bounds__(256) void gemm_bias_k(
    const float* __restrict__ A, const float* __restrict__ B,
    const float* __restrict__ bias, TOUT* __restrict__ C,
    int M, int N, int K)
{
    __shared__ float As[64][33];
    __shared__ float Bs[32][65];
    const int tid = threadIdx.x;
    const int tx = tid & 15, ty = tid >> 4;
    const int rowBase = blockIdx.x * 64;
    const int colBase = blockIdx.y * 64;
    float acc[4][4] = {};

    for (int k0 = 0; k0 < K; k0 += 32) {
        {   // stage A 64x32
            const int r = tid >> 3;
            const int c = (tid & 7) << 2;
            #pragma unroll
            for (int rr = 0; rr < 2; ++rr) {
                const int row = rowBase + r + rr * 32;
                float v[4] = {0.f, 0.f, 0.f, 0.f};
                if (row < M) loadA4(A + (size_t)row * K + k0 + c, v);
                As[r + rr * 32][c + 0] = v[0];
                As[r + rr * 32][c + 1] = v[1];
                As[r + rr * 32][c + 2] = v[2];
                As[r + rr * 32][c + 3] = v[3];
            }
        }
        {   // stage B 32x64
            const int r = tid >> 4;
            const int c = (tid & 15) << 2;
            #pragma unroll
            for (int rr = 0; rr < 2; ++rr) {
                float4 v = *(const float4*)(B + (size_t)(k0 + r + rr * 16) * N + colBase + c);
                Bs[r + rr * 16][c + 0] = v.x;
                Bs[r + rr * 16][c + 1] = v.y;
                Bs[r + rr * 16][c + 2] = v.z;
                Bs[r + rr * 16][c + 3] = v.w;
            }
        }
        __syncthreads();
        #pragma unroll
        for (int kk = 0; kk < 32; ++kk) {
            float a[4], b[4];
            #pragma unroll
            for (int i = 0; i < 4; ++i) a[i] = As[ty * 4 + i][kk];
            #pragma unroll
            for (int j = 0; j < 4; ++j) b[j] = Bs[kk][tx * 4 + j];
            #pragma unroll
            for (int i = 0; i < 4; ++i)
                #pragma unroll
                for (int j = 0; j < 4; ++j)
                    acc[i][j] += a[i] * b[j];
        }
        __syncthreads();
    }

    #pragma unroll
    for (int i = 0; i < 4; ++i) {
        const int row = rowBase + ty * 4 + i;
        if (row >= M) continue;
        #pragma unroll
        for (int j = 0; j < 4; ++j) {
            const int col = colBase + tx * 4 + j;
            float v = acc[i][j] + bias[col];
            if (RELU) v = fmaxf(v, 0.f);
            storeC(C + (size_t)row * N + col, v);
        }
    }
}

// ------- GEMM (N=256 fixed) + bias + residual + LayerNorm fused -------
template<typename TA>
__global__ __launch_bounds__(256) void gemm_res_ln_k(
    const TA* __restrict__ A, const float* __restrict__ B,
    const float* __restrict__ bias, const float* __restrict__ resid,
    const float* __restrict__ gamma, const float* __restrict__ beta,
    float* __restrict__ Out, int M, int K)
{
    __shared__ float As[64][33];
    __shared__ float Bs[32][257];
    __shared__ float ps[64][17];
    __shared__ float pq[64][17];
    __shared__ float mu_s[64], rs_s[64];
    const int tid = threadIdx.x;
    const int tx = tid & 15, ty = tid >> 4;
    const int rowBase = blockIdx.x * 64;
    float acc[4][16] = {};

    for (int k0 = 0; k0 < K; k0 += 32) {
        {   // stage A 64x32
            const int r = tid >> 3;
            const int c = (tid & 7) << 2;
            #pragma unroll
            for (int rr = 0; rr < 2; ++rr) {
                const int row = rowBase + r + rr * 32;
                float v[4] = {0.f, 0.f, 0.f, 0.f};
                if (row < M) loadA4(A + (size_t)row * K + k0 + c, v);
                As[r + rr * 32][c + 0] = v[0];
                As[r + rr * 32][c + 1] = v[1];
                As[r + rr * 32][c + 2] = v[2];
                As[r + rr * 32][c + 3] = v[3];
            }
        }
        {   // stage B 32x256
            #pragma unroll
            for (int it = 0; it < 8; ++it) {
                const int idx = (tid + it * 256) << 2;   // 0..8188
                const int r = idx >> 8;
                const int c = idx & 255;
                float4 v = *(const float4*)(B + (size_t)(k0 + r) * 256 + c);
                Bs[r][c + 0] = v.x; Bs[r][c + 1] = v.y;
                Bs[r][c + 2] = v.z; Bs[r][c + 3] = v.w;
            }
        }
        __syncthreads();
        #pragma unroll
        for (int kk = 0; kk < 32; ++kk) {
            float a[4];
            #pragma unroll
            for (int i = 0; i < 4; ++i) a[i] = As[ty * 4 + i][kk];
            #pragma unroll
            for (int j = 0; j < 16; ++j) {
                const float b = Bs[kk][j * 16 + tx];   // conflict-free: lanes hit distinct banks
                #pragma unroll
                for (int i = 0; i < 4; ++i) acc[i][j] += a[i] * b;
            }
        }
        __syncthreads();
    }

    // epilogue: +bias +resid, then LayerNorm per row
    #pragma unroll
    for (int i = 0; i < 4; ++i) {
        const int row = rowBase + ty * 4 + i;
        float s = 0.f, q = 0.f;
        #pragma unroll
        for (int j = 0; j < 16; ++j) {
            const int col = j * 16 + tx;
            float v = acc[i][j] + bias[col];
            if (row < M) v += resid[(size_t)row * 256 + col];
            acc[i][j] = v;
            s += v; q += v * v;
        }
        ps[ty * 4 + i][tx] = s;
        pq[ty * 4 + i][tx] = q;
    }
    __syncthreads();
    if (tid < 64) {
        float s = 0.f, q = 0.f;
        #pragma unroll
        for (int t = 0; t < 16; ++t) { s += ps[tid][t]; q += pq[tid][t]; }
        const float m = s * (1.f / 256.f);
        const float var = q * (1.f / 256.f) - m * m;
        mu_s[tid] = m;
        rs_s[tid] = rsqrtf(var + 1e-5f);
    }
    __syncthreads();
    #pragma unroll
    for (int i = 0; i < 4; ++i) {
        const int row = rowBase + ty * 4 + i;
        if (row >= M) continue;
        const float m = mu_s[ty * 4 + i], r = rs_s[ty * 4 + i];
        #pragma unroll
        for (int j = 0; j < 16; ++j) {
            const int col = j * 16 + tx;
            Out[(size_t)row * 256 + col] = (acc[i][j] - m) * r * gamma[col] + beta[col];
        }
    }
}

// ------- softmax(attn logits) + sampling-loc computation -------
// block = 128 threads, one per (m,l,p); grid = (LQ, NBATCH)
__global__ __launch_bounds__(128) void loc_attn_k(
    const float* __restrict__ rawoff, const float* __restrict__ rawattn,
    const float* __restrict__ refpts,
    float* __restrict__ loc_o, float* __restrict__ attn_o)
{
    constexpr float LVL_Wf[4] = {152.f, 76.f, 38.f, 19.f};
    constexpr float LVL_Hf[4] = {100.f, 50.f, 25.f, 13.f};
    const int q = blockIdx.x, n = blockIdx.y;
    const size_t row = (size_t)n * LQ + q;
    const int tid = threadIdx.x;          // = m*32 + l*8 + p

    float logit = rawattn[row * 128 + tid];
    float mx = logit;
    #pragma unroll
    for (int o = 16; o; o >>= 1) mx = fmaxf(mx, __shfl_xor(mx, o, 32));
    float e = expf(logit - mx);
    float s = e;
    #pragma unroll
    for (int o = 16; o; o >>= 1) s += __shfl_xor(s, o, 32);
    attn_o[row * 128 + tid] = e / s;

    const int l = (tid >> 3) & 3;
    const float ox = rawoff[row * 256 + tid * 2 + 0];
    const float oy = rawoff[row * 256 + tid * 2 + 1];
    const float rx = refpts[(row * 4 + l) * 2 + 0];
    const float ry = refpts[(row * 4 + l) * 2 + 1];
    loc_o[row * 256 + tid * 2 + 0] = rx + ox / LVL_Wf[l];
    loc_o[row * 256 + tid * 2 + 1] = ry + oy / LVL_Hf[l];
}

// ------- deformable bilinear sampling + attention-weighted sum -------
// block = 256 threads, one per output channel c = m*64+d; grid = (LQ, NBATCH)
__global__ __launch_bounds__(256) void sample_k(
    const float* __restrict__ value, const float* __restrict__ loc_i,
    const float* __restrict__ attn_i, float* __restrict__ samp_o)
{
    constexpr int LVL_H[4] = {100, 50, 25, 13};
    constexpr int LVL_W[4] = {152, 76, 38, 19};
    constexpr int LVL_S[4] = {0, 15200, 19000, 19950};
    const int q = blockIdx.x, n = blockIdx.y;
    const size_t row = (size_t)n * LQ + q;
    const int tid = threadIdx.x;

    __shared__ float loc_s[256];
    __shared__ float attn_s[128];
    loc_s[tid] = loc_i[row * 256 + tid];
    if (tid < 128) attn_s[tid] = attn_i[row * 128 + tid];
    __syncthreads();

    const int m = tid >> 6, d = tid & 63;
    const float* vbase = value + ((size_t)n * LQ) * 256 + m * 64 + d;
    float acc = 0.f;
    #pragma unroll
    for (int l = 0; l < 4; ++l) {
        const int H = LVL_H[l], W = LVL_W[l], st = LVL_S[l];
        #pragma unroll
        for (int p = 0; p < 8; ++p) {
            const int idx = (m * 4 + l) * 8 + p;
            const float lx = loc_s[idx * 2 + 0];
            const float ly = loc_s[idx * 2 + 1];
            const float a = attn_s[idx];
            const float x = lx * (float)W - 0.5f;
            const float y = ly * (float)H - 0.5f;
            const float x0f = floorf(x), y0f = floorf(y);
            const float wx = x - x0f, wy = y - y0f;
            const int x0 = (int)x0f, y0 = (int)y0f;
            #pragma unroll
            for (int dy = 0; dy < 2; ++dy) {
                #pragma unroll
                for (int dx = 0; dx < 2; ++dx) {
                    const int xi = x0 + dx, yi = y0 + dy;
                    if (xi >= 0 && xi < W && yi >= 0 && yi < H) {
                        const float w = (dx ? wx : 1.f - wx) * (dy ? wy : 1.f - wy);
                        acc += a * w * vbase[(size_t)(st + yi * W + xi) * 256];
                    }
                }
            }
        }
    }
    samp_o[row * 256 + tid] = acc;
}

extern "C" void kernel_launch(void* const* d_in, const int* in_sizes, int n_in,
                              void* d_out, int out_size, void* d_ws, size_t ws_size,
                              hipStream_t stream)
{
    const float* src_feat = (const float*)d_in[0];
    const float* refpts   = (const float*)d_in[1];
    const float* key_feat = (const float*)d_in[2];
    const float* W_off  = (const float*)d_in[5];
    const float* b_off  = (const float*)d_in[6];
    const float* W_attn = (const float*)d_in[7];
    const float* b_attn = (const float*)d_in[8];
    const float* W_val  = (const float*)d_in[9];
    const float* b_val  = (const float*)d_in[10];
    const float* W_out  = (const float*)d_in[11];
    const float* b_out  = (const float*)d_in[12];
    const float* W1  = (const float*)d_in[13];
    const float* b1  = (const float*)d_in[14];
    const float* W2  = (const float*)d_in[15];
    const float* b2  = (const float*)d_in[16];
    const float* g1  = (const float*)d_in[17];
    const float* be1 = (const float*)d_in[18];
    const float* g2  = (const float*)d_in[19];
    const float* be2 = (const float*)d_in[20];

    float* out = (float*)d_out;
    float* x_out    = out;                           // (MROWS,256)
    float* loc_out  = out + (size_t)MROWS * 256;     // (MROWS,4,4,8,2)
    float* attn_out = out + (size_t)MROWS * 512;     // (MROWS,4,4,8)

    char* ws = (char*)d_ws;
    float* value   = (float*)ws;                                   // 41.4 MB
    float* rawoff  = (float*)(ws + (size_t)MROWS * 256 * 4);       // 41.4 MB
    float* rawattn = rawoff + (size_t)MROWS * 256;                 // 20.7 MB
    float* sampout = rawoff;                                       // reuse after loc_attn
    __hip_bfloat16* Hbuf = (__hip_bfloat16*)ws;                    // 82.7 MB, reuse after LN1

    const dim3 blk(256);
    const int RB = (MROWS + 63) / 64;   // 632 row-blocks

    // value = key_feat @ W_val + b_val
    gemm_bias_k<float, false><<<dim3(RB, 4), blk, 0, stream>>>(key_feat, W_val, b_val, value, MROWS, 256, 256);
    // raw offsets / attn logits
    gemm_bias_k<float, false><<<dim3(RB, 4), blk, 0, stream>>>(src_feat, W_off, b_off, rawoff, MROWS, 256, 256);
    gemm_bias_k<float, false><<<dim3(RB, 2), blk, 0, stream>>>(src_feat, W_attn, b_attn, rawattn, MROWS, 128, 256);
    // softmax + loc -> written directly to outputs
    loc_attn_k<<<dim3(LQ, NBATCH), dim3(128), 0, stream>>>(rawoff, rawattn, refpts, loc_out, attn_out);
    // deformable sampling
    sample_k<<<dim3(LQ, NBATCH), blk, 0, stream>>>(value, loc_out, attn_out, sampout);
    // out-proj + residual + LN1 -> x (stored in d_out x-region)
    gemm_res_ln_k<float><<<dim3(RB), blk, 0, stream>>>(sampout, W_out, b_out, src_feat, g1, be1, x_out, MROWS, 256);
    // FFN: H = relu(x@W1+b1) stored bf16
    gemm_bias_k<__hip_bfloat16, true><<<dim3(RB, 16), blk, 0, stream>>>(x_out, W1, b1, Hbuf, MROWS, 1024, 256);
    // FFN out + residual + LN2 -> final x (in place)
    gemm_res_ln_k<__hip_bfloat16><<<dim3(RB), blk, 0, stream>>>(Hbuf, W2, b2, x_out, g2, be2, x_out, MROWS, 1024);
}

// Round 2
// 1662.223 us; speedup vs baseline: 1.2973x; 1.2973x over previous
//
#include <hip/hip_runtime.h>
#include <hip/hip_bf16.h>

#define LQ 20197
#define NBATCH 2
#define MROWS (NBATCH * LQ)   // 40394

__device__ __forceinline__ void loadA4(const float* p, float o[4]) {
    float4 v = *(const float4*)p;
    o[0] = v.x; o[1] = v.y; o[2] = v.z; o[3] = v.w;
}
__device__ __forceinline__ void loadA4(const __hip_bfloat16* p, float o[4]) {
    ushort4 u = *(const ushort4*)p;
    o[0] = __uint_as_float((unsigned)u.x << 16);
    o[1] = __uint_as_float((unsigned)u.y << 16);
    o[2] = __uint_as_float((unsigned)u.z << 16);
    o[3] = __uint_as_float((unsigned)u.w << 16);
}

__device__ __forceinline__ void storeC(float* p, float v) { *p = v; }
__device__ __forceinline__ void storeC(__hip_bfloat16* p, float v) { *p = __float2bfloat16(v); }

// ---------------- generic tiled GEMM: C = A(MxK) @ B(KxN) + bias ----------------
// BM=64, BN=64, BK=32, 256 threads, 4x4 microtile.
template<typename TOUT, bool RELU>
__global__ __launch_bounds__(256) void gemm_bias_k(
    const float* __restrict__ A, const float* __restrict__ B,
    const float* __restrict__ bias, TOUT* __restrict__ C,
    int M, int N, int K)
{
    __shared__ float As[64][33];
    __shared__ float Bs[32][65];
    const int tid = threadIdx.x;
    const int tx = tid & 15, ty = tid >> 4;
    const int rowBase = blockIdx.x * 64;
    const int colBase = blockIdx.y * 64;
    float acc[4][4] = {};

    for (int k0 = 0; k0 < K; k0 += 32) {
        {   // stage A 64x32
            const int r = tid >> 3;
            const int c = (tid & 7) << 2;
            #pragma unroll
            for (int rr = 0; rr < 2; ++rr) {
                const int row = rowBase + r + rr * 32;
                float v[4] = {0.f, 0.f, 0.f, 0.f};
                if (row < M) loadA4(A + (size_t)row * K + k0 + c, v);
                As[r + rr * 32][c + 0] = v[0];
                As[r + rr * 32][c + 1] = v[1];
                As[r + rr * 32][c + 2] = v[2];
                As[r + rr * 32][c + 3] = v[3];
            }
        }
        {   // stage B 32x64
            const int r = tid >> 4;
            const int c = (tid & 15) << 2;
            #pragma unroll
            for (int rr = 0; rr < 2; ++rr) {
                float4 v = *(const float4*)(B + (size_t)(k0 + r + rr * 16) * N + colBase + c);
                Bs[r + rr * 16][c + 0] = v.x;
                Bs[r + rr * 16][c + 1] = v.y;
                Bs[r + rr * 16][c + 2] = v.z;
                Bs[r + rr * 16][c + 3] = v.w;
            }
        }
        __syncthreads();
        #pragma unroll
        for (int kk = 0; kk < 32; ++kk) {
            float a[4], b[4];
            #pragma unroll
            for (int i = 0; i < 4; ++i) a[i] = As[ty * 4 + i][kk];
            #pragma unroll
            for (int j = 0; j < 4; ++j) b[j] = Bs[kk][tx * 4 + j];
            #pragma unroll
            for (int i = 0; i < 4; ++i)
                #pragma unroll
                for (int j = 0; j < 4; ++j)
                    acc[i][j] += a[i] * b[j];
        }
        __syncthreads();
    }

    #pragma unroll
    for (int i = 0; i < 4; ++i) {
        const int row = rowBase + ty * 4 + i;
        if (row >= M) continue;
        #pragma unroll
        for (int j = 0; j < 4; ++j) {
            const int col = colBase + tx * 4 + j;
            float v = acc[i][j] + bias[col];
            if (RELU) v = fmaxf(v, 0.f);
            storeC(C + (size_t)row * N + col, v);
        }
    }
}

// ------- GEMM (N=256 fixed) + bias + residual + LayerNorm fused -------
template<typename TA>
__global__ __launch_bounds__(256) void gemm_res_ln_k(
    const TA* __restrict__ A, const float* __restrict__ B,
    const float* __restrict__ bias, const float* __restrict__ resid,
    const float* __restrict__ gamma, const float* __restrict__ beta,
    float* __restrict__ Out, int M, int K)
{
    __shared__ float As[64][33];
    __shared__ float Bs[32][257];
    __shared__ float ps[64][17];
    __shared__ float pq[64][17];
    __shared__ float mu_s[64], rs_s[64];
    const int tid = threadIdx.x;
    const int tx = tid & 15, ty = tid >> 4;
    const int rowBase = blockIdx.x * 64;
    float acc[4][16] = {};

    for (int k0 = 0; k0 < K; k0 += 32) {
        {   // stage A 64x32
            const int r = tid >> 3;
            const int c = (tid & 7) << 2;
            #pragma unroll
            for (int rr = 0; rr < 2; ++rr) {
                const int row = rowBase + r + rr * 32;
                float v[4] = {0.f, 0.f, 0.f, 0.f};
                if (row < M) loadA4(A + (size_t)row * K + k0 + c, v);
                As[r + rr * 32][c + 0] = v[0];
                As[r + rr * 32][c + 1] = v[1];
                As[r + rr * 32][c + 2] = v[2];
                As[r + rr * 32][c + 3] = v[3];
            }
        }
        {   // stage B 32x256
            #pragma unroll
            for (int it = 0; it < 8; ++it) {
                const int idx = (tid + it * 256) << 2;   // 0..8188
                const int r = idx >> 8;
                const int c = idx & 255;
                float4 v = *(const float4*)(B + (size_t)(k0 + r) * 256 + c);
                Bs[r][c + 0] = v.x; Bs[r][c + 1] = v.y;
                Bs[r][c + 2] = v.z; Bs[r][c + 3] = v.w;
            }
        }
        __syncthreads();
        #pragma unroll
        for (int kk = 0; kk < 32; ++kk) {
            float a[4];
            #pragma unroll
            for (int i = 0; i < 4; ++i) a[i] = As[ty * 4 + i][kk];
            #pragma unroll
            for (int j = 0; j < 16; ++j) {
                const float b = Bs[kk][j * 16 + tx];
                #pragma unroll
                for (int i = 0; i < 4; ++i) acc[i][j] += a[i] * b;
            }
        }
        __syncthreads();
    }

    // epilogue: +bias +resid, then LayerNorm per row
    #pragma unroll
    for (int i = 0; i < 4; ++i) {
        const int row = rowBase + ty * 4 + i;
        float s = 0.f, q = 0.f;
        #pragma unroll
        for (int j = 0; j < 16; ++j) {
            const int col = j * 16 + tx;
            float v = acc[i][j] + bias[col];
            if (row < M) v += resid[(size_t)row * 256 + col];
            acc[i][j] = v;
            s += v; q += v * v;
        }
        ps[ty * 4 + i][tx] = s;
        pq[ty * 4 + i][tx] = q;
    }
    __syncthreads();
    if (tid < 64) {
        float s = 0.f, q = 0.f;
        #pragma unroll
        for (int t = 0; t < 16; ++t) { s += ps[tid][t]; q += pq[tid][t]; }
        const float m = s * (1.f / 256.f);
        const float var = q * (1.f / 256.f) - m * m;
        mu_s[tid] = m;
        rs_s[tid] = rsqrtf(var + 1e-5f);
    }
    __syncthreads();
    #pragma unroll
    for (int i = 0; i < 4; ++i) {
        const int row = rowBase + ty * 4 + i;
        if (row >= M) continue;
        const float m = mu_s[ty * 4 + i], r = rs_s[ty * 4 + i];
        #pragma unroll
        for (int j = 0; j < 16; ++j) {
            const int col = j * 16 + tx;
            Out[(size_t)row * 256 + col] = (acc[i][j] - m) * r * gamma[col] + beta[col];
        }
    }
}

// ------- softmax(attn logits) + sampling-loc computation -------
__global__ __launch_bounds__(128) void loc_attn_k(
    const float* __restrict__ rawoff, const float* __restrict__ rawattn,
    const float* __restrict__ refpts,
    float* __restrict__ loc_o, float* __restrict__ attn_o)
{
    constexpr float LVL_Wf[4] = {152.f, 76.f, 38.f, 19.f};
    constexpr float LVL_Hf[4] = {100.f, 50.f, 25.f, 13.f};
    const int q = blockIdx.x, n = blockIdx.y;
    const size_t row = (size_t)n * LQ + q;
    const int tid = threadIdx.x;          // = m*32 + l*8 + p

    float logit = rawattn[row * 128 + tid];
    float mx = logit;
    #pragma unroll
    for (int o = 16; o; o >>= 1) mx = fmaxf(mx, __shfl_xor(mx, o, 32));
    float e = expf(logit - mx);
    float s = e;
    #pragma unroll
    for (int o = 16; o; o >>= 1) s += __shfl_xor(s, o, 32);
    attn_o[row * 128 + tid] = e / s;

    const int l = (tid >> 3) & 3;
    const float ox = rawoff[row * 256 + tid * 2 + 0];
    const float oy = rawoff[row * 256 + tid * 2 + 1];
    const float rx = refpts[(row * 4 + l) * 2 + 0];
    const float ry = refpts[(row * 4 + l) * 2 + 1];
    loc_o[row * 256 + tid * 2 + 0] = rx + ox / LVL_Wf[l];
    loc_o[row * 256 + tid * 2 + 1] = ry + oy / LVL_Hf[l];
}

// ------- deformable bilinear sampling + attention-weighted sum -------
// Phase 1: per-query tap (idx, w) precompute into LDS (once, not 64x per channel).
// Phase 2: each thread gathers 4 channels (ushort4 bf16 loads) for one query.
// Block = 256 threads = QB(4) queries x 64 channel-chunks.
#define QB 4
__global__ __launch_bounds__(256) void sample_k(
    const __hip_bfloat16* __restrict__ value, const float* __restrict__ loc_i,
    const float* __restrict__ attn_i, float* __restrict__ samp_o)
{
    constexpr int LVL_H[4] = {100, 50, 25, 13};
    constexpr int LVL_W[4] = {152, 76, 38, 19};
    constexpr int LVL_S[4] = {0, 15200, 19000, 19950};
    const int tid = threadIdx.x;
    const int rowBase = blockIdx.x * QB;

    __shared__ int   sIdx[QB][128][4];
    __shared__ float sW[QB][128][4];

    // ---- phase 1: 512 tap-items, 2 per thread ----
    #pragma unroll
    for (int it = 0; it < 2; ++it) {
        const int item = tid + it * 256;       // 0..511
        const int qs = item >> 7;              // 0..3
        const int t  = item & 127;             // m*32 + l*8 + p
        const int row = rowBase + qs;
        if (row < MROWS) {
            const int l = (t >> 3) & 3;
            const int n = (row >= LQ) ? 1 : 0;
            const int H = LVL_H[l], W = LVL_W[l];
            const float lx = loc_i[(size_t)row * 256 + t * 2 + 0];
            const float ly = loc_i[(size_t)row * 256 + t * 2 + 1];
            const float a  = attn_i[(size_t)row * 128 + t];
            const float x = lx * (float)W - 0.5f;
            const float y = ly * (float)H - 0.5f;
            const float x0f = floorf(x), y0f = floorf(y);
            const float wx = x - x0f, wy = y - y0f;
            const int x0 = (int)x0f, y0 = (int)y0f;
            const int base = n * LQ + LVL_S[l];
            #pragma unroll
            for (int nb = 0; nb < 4; ++nb) {
                const int dx = nb & 1, dy = nb >> 1;
                const int xi = x0 + dx, yi = y0 + dy;
                const bool valid = (xi >= 0) & (xi < W) & (yi >= 0) & (yi < H);
                const float w = (dx ? wx : 1.f - wx) * (dy ? wy : 1.f - wy) * a;
                sW[qs][t][nb]   = valid ? w : 0.f;
                sIdx[qs][t][nb] = valid ? (base + yi * W + xi) : 0;
            }
        }
    }
    __syncthreads();

    // ---- phase 2: gather. thread = (qs, c4); channels [c4*4, c4*4+4) ----
    const int qs = tid >> 6;
    const int c4 = tid & 63;
    const int row = rowBase + qs;
    if (row >= MROWS) return;
    const int m = c4 >> 4;
    const __hip_bfloat16* vbase = value + c4 * 4;
    const int tbase = m * 32;

    float4 acc = {0.f, 0.f, 0.f, 0.f};
    #pragma unroll
    for (int t = 0; t < 32; ++t) {
        #pragma unroll
        for (int nb = 0; nb < 4; ++nb) {
            const float w = sW[qs][tbase + t][nb];
            if (w != 0.f) {
                const int idx = sIdx[qs][tbase + t][nb];
                const ushort4 u = *(const ushort4*)(vbase + (size_t)idx * 256);
                acc.x += w * __uint_as_float((unsigned)u.x << 16);
                acc.y += w * __uint_as_float((unsigned)u.y << 16);
                acc.z += w * __uint_as_float((unsigned)u.z << 16);
                acc.w += w * __uint_as_float((unsigned)u.w << 16);
            }
        }
    }
    *(float4*)(samp_o + (size_t)row * 256 + c4 * 4) = acc;
}

extern "C" void kernel_launch(void* const* d_in, const int* in_sizes, int n_in,
                              void* d_out, int out_size, void* d_ws, size_t ws_size,
                              hipStream_t stream)
{
    const float* src_feat = (const float*)d_in[0];
    const float* refpts   = (const float*)d_in[1];
    const float* key_feat = (const float*)d_in[2];
    const float* W_off  = (const float*)d_in[5];
    const float* b_off  = (const float*)d_in[6];
    const float* W_attn = (const float*)d_in[7];
    const float* b_attn = (const float*)d_in[8];
    const float* W_val  = (const float*)d_in[9];
    const float* b_val  = (const float*)d_in[10];
    const float* W_out  = (const float*)d_in[11];
    const float* b_out  = (const float*)d_in[12];
    const float* W1  = (const float*)d_in[13];
    const float* b1  = (const float*)d_in[14];
    const float* W2  = (const float*)d_in[15];
    const float* b2  = (const float*)d_in[16];
    const float* g1  = (const float*)d_in[17];
    const float* be1 = (const float*)d_in[18];
    const float* g2  = (const float*)d_in[19];
    const float* be2 = (const float*)d_in[20];

    float* out = (float*)d_out;
    float* x_out    = out;                           // (MROWS,256)
    float* loc_out  = out + (size_t)MROWS * 256;     // (MROWS,4,4,8,2)
    float* attn_out = out + (size_t)MROWS * 512;     // (MROWS,4,4,8)

    char* ws = (char*)d_ws;
    __hip_bfloat16* value = (__hip_bfloat16*)ws;                   // 20.7 MB (bf16)
    float* rawoff  = (float*)(ws + (size_t)MROWS * 256 * 4);       // 41.4 MB
    float* rawattn = rawoff + (size_t)MROWS * 256;                 // 20.7 MB
    float* sampout = rawoff;                                       // reuse after loc_attn
    __hip_bfloat16* Hbuf = (__hip_bfloat16*)ws;                    // 82.7 MB, reuse after sampling

    const dim3 blk(256);
    const int RB = (MROWS + 63) / 64;   // 632 row-blocks

    // value = key_feat @ W_val + b_val  (bf16 output for cheap gathers)
    gemm_bias_k<__hip_bfloat16, false><<<dim3(RB, 4), blk, 0, stream>>>(key_feat, W_val, b_val, value, MROWS, 256, 256);
    // raw offsets / attn logits
    gemm_bias_k<float, false><<<dim3(RB, 4), blk, 0, stream>>>(src_feat, W_off, b_off, rawoff, MROWS, 256, 256);
    gemm_bias_k<float, false><<<dim3(RB, 2), blk, 0, stream>>>(src_feat, W_attn, b_attn, rawattn, MROWS, 128, 256);
    // softmax + loc -> written directly to outputs
    loc_attn_k<<<dim3(LQ, NBATCH), dim3(128), 0, stream>>>(rawoff, rawattn, refpts, loc_out, attn_out);
    // deformable sampling
    sample_k<<<dim3((MROWS + QB - 1) / QB), blk, 0, stream>>>(value, loc_out, attn_out, sampout);
    // out-proj + residual + LN1 -> x (stored in d_out x-region)
    gemm_res_ln_k<float><<<dim3(RB), blk, 0, stream>>>(sampout, W_out, b_out, src_feat, g1, be1, x_out, MROWS, 256);
    // FFN: H = relu(x@W1+b1) stored bf16
    gemm_bias_k<__hip_bfloat16, true><<<dim3(RB, 16), blk, 0, stream>>>(x_out, W1, b1, Hbuf, MROWS, 1024, 256);
    // FFN out + residual + LN2 -> final x (in place)
    gemm_res_ln_k<__hip_bfloat16><<<dim3(RB), blk, 0, stream>>>(Hbuf, W2, b2, x_out, g2, be2, x_out, MROWS, 1024);
}

// Round 3
// 616.668 us; speedup vs baseline: 3.4968x; 2.6955x over previous
//
#include <hip/hip_runtime.h>
#include <hip/hip_bf16.h>

#define LQ 20197
#define NBATCH 2
#define MROWS 40394
#define MR256 ((size_t)MROWS * 256)

typedef __attribute__((ext_vector_type(8))) short bf16x8;
typedef __attribute__((ext_vector_type(4))) float f32x4;

__device__ __forceinline__ unsigned short f2bf(float f) {
    unsigned u = __float_as_uint(f);
    return (unsigned short)((u + 0x7fff + ((u >> 16) & 1)) >> 16);   // RNE
}
__device__ __forceinline__ float bf2f(unsigned short b) {
    return __uint_as_float((unsigned)b << 16);
}

// ---------------- prep: fp32->bf16 conversions + weight transposes ----------------
__global__ __launch_bounds__(256) void prep_k(
    const float* __restrict__ src, const float* __restrict__ key,
    const float* __restrict__ Wv, const float* __restrict__ Wo,
    const float* __restrict__ Wa, const float* __restrict__ Wu,
    const float* __restrict__ W1, const float* __restrict__ W2,
    const float* __restrict__ ba,
    unsigned short* __restrict__ srcb, unsigned short* __restrict__ keyb,
    unsigned short* __restrict__ BTv, unsigned short* __restrict__ BTo,
    unsigned short* __restrict__ BTa, unsigned short* __restrict__ BTu,
    unsigned short* __restrict__ BT1, unsigned short* __restrict__ BT2,
    float* __restrict__ battn)
{
    const size_t id0 = (size_t)blockIdx.x * blockDim.x + threadIdx.x;
    const size_t stride = (size_t)gridDim.x * blockDim.x;
    const size_t NC = MR256 / 4;
    for (size_t i = id0; i < NC; i += stride) {
        float4 v = ((const float4*)src)[i];
        ((ushort4*)srcb)[i] = make_ushort4(f2bf(v.x), f2bf(v.y), f2bf(v.z), f2bf(v.w));
        float4 u = ((const float4*)key)[i];
        ((ushort4*)keyb)[i] = make_ushort4(f2bf(u.x), f2bf(u.y), f2bf(u.z), f2bf(u.w));
    }
    for (size_t i = id0; i < 65536; i += stride) {
        const int n = (int)(i >> 8), k = (int)(i & 255);
        BTv[i] = f2bf(Wv[k * 256 + n]);
        BTo[i] = f2bf(Wo[k * 256 + n]);
        BTu[i] = f2bf(Wu[k * 256 + n]);
        BTa[i] = (n < 128) ? f2bf(Wa[k * 128 + n]) : (unsigned short)0;
    }
    for (size_t i = id0; i < 262144; i += stride) {
        const int n = (int)(i >> 8), k = (int)(i & 255);      // BT1 [1024][256]
        BT1[i] = f2bf(W1[(size_t)k * 1024 + n]);
        const int n2 = (int)(i >> 10), k2 = (int)(i & 1023);  // BT2 [256][1024]
        BT2[i] = f2bf(W2[(size_t)k2 * 256 + n2]);
    }
    if (id0 < 256) battn[id0] = (id0 < 128) ? ba[id0] : 0.f;
}

// ---------------- MFMA GEMM: 64x256 tile, K=256, 4 waves ----------------
// A [M][256] bf16, BT [256][256] bf16 (row n = output col), XOR-swizzled LDS.
enum { EP_VAL = 0, EP_LOC = 1, EP_ATTN = 2, EP_LN = 3 };

template<int EP>
__global__ __launch_bounds__(256) void gemm_k(
    const unsigned short* A, const unsigned short* __restrict__ BT,
    const float* __restrict__ bias, const float* __restrict__ aux,
    const float* __restrict__ g, const float* __restrict__ be,
    void* outp)
{
    __shared__ __align__(16) unsigned short As[64 * 64];
    __shared__ __align__(16) unsigned short Bs[256 * 64];
    __shared__ float ps[64][4], pq[64][4];
    __shared__ float mu_s[64], rs_s[64];

    const int tid = threadIdx.x;
    const int l = tid & 63, w = tid >> 6;
    const int lc = l & 15, rg = l >> 4;
    const int rowBase = blockIdx.x * 64;

    f32x4 acc[4][4] = {};

    for (int k0 = 0; k0 < 256; k0 += 64) {
        if (k0) __syncthreads();
        #pragma unroll
        for (int p = 0; p < 2; ++p) {           // stage A 64x64
            const int idx = tid + p * 256;
            const int r = idx >> 3, s = idx & 7;
            const int row = rowBase + r;
            bf16x8 v = {};
            if (row < MROWS) v = *(const bf16x8*)(A + (size_t)row * 256 + k0 + s * 8);
            *(bf16x8*)&As[r * 64 + ((s ^ (r & 7)) << 3)] = v;
        }
        #pragma unroll
        for (int p = 0; p < 8; ++p) {           // stage B 256x64
            const int idx = tid + p * 256;
            const int n = idx >> 3, s = idx & 7;
            bf16x8 v = *(const bf16x8*)(BT + (size_t)n * 256 + k0 + s * 8);
            *(bf16x8*)&Bs[n * 64 + ((s ^ (n & 7)) << 3)] = v;
        }
        __syncthreads();
        #pragma unroll
        for (int kk = 0; kk < 2; ++kk) {
            bf16x8 aF[4], bF[4];
            const int sl = kk * 4 + rg;
            #pragma unroll
            for (int i = 0; i < 4; ++i) {
                const int r = i * 16 + lc;
                aF[i] = *(const bf16x8*)&As[r * 64 + ((sl ^ (r & 7)) << 3)];
            }
            #pragma unroll
            for (int j = 0; j < 4; ++j) {
                const int n = w * 64 + j * 16 + lc;
                bF[j] = *(const bf16x8*)&Bs[n * 64 + ((sl ^ (n & 7)) << 3)];
            }
            #pragma unroll
            for (int i = 0; i < 4; ++i)
                #pragma unroll
                for (int j = 0; j < 4; ++j)
                    acc[i][j] = __builtin_amdgcn_mfma_f32_16x16x32_bf16(aF[i], bF[j], acc[i][j], 0, 0, 0);
        }
    }

    if (EP == EP_VAL) {
        unsigned short* out = (unsigned short*)outp;
        #pragma unroll
        for (int i = 0; i < 4; ++i)
            #pragma unroll
            for (int r4 = 0; r4 < 4; ++r4) {
                const int row = rowBase + i * 16 + rg * 4 + r4;
                if (row >= MROWS) continue;
                #pragma unroll
                for (int j = 0; j < 4; ++j) {
                    const int col = w * 64 + j * 16 + lc;
                    out[(size_t)row * 256 + col] = f2bf(acc[i][j][r4] + bias[col]);
                }
            }
    } else if (EP == EP_LOC) {
        float* out = (float*)outp;
        const float INV[8] = {1.f/152, 1.f/100, 1.f/76, 1.f/50, 1.f/38, 1.f/25, 1.f/19, 1.f/13};
        #pragma unroll
        for (int i = 0; i < 4; ++i)
            #pragma unroll
            for (int r4 = 0; r4 < 4; ++r4) {
                const int row = rowBase + i * 16 + rg * 4 + r4;
                if (row >= MROWS) continue;
                #pragma unroll
                for (int j = 0; j < 4; ++j) {
                    const int col = w * 64 + j * 16 + lc;
                    const int lvlxy = (col >> 3) & 7;   // hmm: lvl = (col>>4)&3, xy = col&1
                    const int lvl = (col >> 4) & 3, xy = col & 1;
                    (void)lvlxy;
                    const float off = acc[i][j][r4] + bias[col];
                    const float ref = aux[(size_t)row * 8 + lvl * 2 + xy];
                    out[(size_t)row * 256 + col] = ref + off * INV[lvl * 2 + xy];
                }
            }
    } else if (EP == EP_ATTN) {
        if (w >= 2) return;                     // cols 128-255 are padding
        float* out = (float*)outp;
        #pragma unroll
        for (int i = 0; i < 4; ++i)
            #pragma unroll
            for (int r4 = 0; r4 < 4; ++r4) {
                const int row = rowBase + i * 16 + rg * 4 + r4;
                float v[4];
                #pragma unroll
                for (int j = 0; j < 4; ++j) v[j] = acc[i][j][r4] + bias[w * 64 + j * 16 + lc];
                // groups: j=0,1 -> head 2w ; j=2,3 -> head 2w+1 (32 cols each)
                float mA = fmaxf(v[0], v[1]), mB = fmaxf(v[2], v[3]);
                #pragma unroll
                for (int o = 1; o <= 8; o <<= 1) {
                    mA = fmaxf(mA, __shfl_xor(mA, o));
                    mB = fmaxf(mB, __shfl_xor(mB, o));
                }
                float e[4];
                e[0] = __expf(v[0] - mA); e[1] = __expf(v[1] - mA);
                e[2] = __expf(v[2] - mB); e[3] = __expf(v[3] - mB);
                float sA = e[0] + e[1], sB = e[2] + e[3];
                #pragma unroll
                for (int o = 1; o <= 8; o <<= 1) {
                    sA += __shfl_xor(sA, o);
                    sB += __shfl_xor(sB, o);
                }
                if (row >= MROWS) continue;
                #pragma unroll
                for (int j = 0; j < 4; ++j) {
                    const int col = w * 64 + j * 16 + lc;   // < 128
                    out[(size_t)row * 128 + col] = e[j] / (j < 2 ? sA : sB);
                }
            }
    } else {   // EP_LN: + bias + resid(fp32 aux) + LayerNorm -> bf16 out
        unsigned short* out = (unsigned short*)outp;
        #pragma unroll
        for (int i = 0; i < 4; ++i)
            #pragma unroll
            for (int r4 = 0; r4 < 4; ++r4) {
                const int row = rowBase + i * 16 + rg * 4 + r4;
                float s = 0.f, q = 0.f;
                #pragma unroll
                for (int j = 0; j < 4; ++j) {
                    const int col = w * 64 + j * 16 + lc;
                    float t = acc[i][j][r4] + bias[col];
                    if (row < MROWS) t += aux[(size_t)row * 256 + col];
                    acc[i][j][r4] = t;
                    s += t; q += t * t;
                }
                #pragma unroll
                for (int o = 1; o <= 8; o <<= 1) { s += __shfl_xor(s, o); q += __shfl_xor(q, o); }
                if (lc == 0) { ps[i * 16 + rg * 4 + r4][w] = s; pq[i * 16 + rg * 4 + r4][w] = q; }
            }
        __syncthreads();
        if (tid < 64) {
            const float s = ps[tid][0] + ps[tid][1] + ps[tid][2] + ps[tid][3];
            const float q = pq[tid][0] + pq[tid][1] + pq[tid][2] + pq[tid][3];
            const float m = s * (1.f / 256.f);
            mu_s[tid] = m;
            rs_s[tid] = rsqrtf(q * (1.f / 256.f) - m * m + 1e-5f);
        }
        __syncthreads();
        #pragma unroll
        for (int i = 0; i < 4; ++i)
            #pragma unroll
            for (int r4 = 0; r4 < 4; ++r4) {
                const int rl = i * 16 + rg * 4 + r4;
                const int row = rowBase + rl;
                if (row >= MROWS) continue;
                const float m = mu_s[rl], r = rs_s[rl];
                #pragma unroll
                for (int j = 0; j < 4; ++j) {
                    const int col = w * 64 + j * 16 + lc;
                    out[(size_t)row * 256 + col] = f2bf((acc[i][j][r4] - m) * r * g[col] + be[col]);
                }
            }
    }
}

// ---------------- fused FFN: x -> relu(x@W1+b1)@W2+b2 + resid + LN2 -> fp32 ----------------
__global__ __launch_bounds__(256, 2) void ffn_k(
    const unsigned short* __restrict__ xb,   // [M][256] bf16 (also resid)
    const unsigned short* __restrict__ BT1,  // [1024][256]
    const float* __restrict__ b1,
    const unsigned short* __restrict__ BT2,  // [256][1024]
    const float* __restrict__ b2,
    const float* __restrict__ g, const float* __restrict__ be,
    float* __restrict__ out)
{
    __shared__ __align__(16) unsigned short As[64 * 64];
    __shared__ __align__(16) unsigned short Bs[256 * 64];
    __shared__ __align__(16) unsigned short Hs[64 * 256];
    __shared__ float ps[64][4], pq[64][4], mu_s[64], rs_s[64];

    const int tid = threadIdx.x;
    const int l = tid & 63, w = tid >> 6;
    const int lc = l & 15, rg = l >> 4;
    const int rowBase = blockIdx.x * 64;

    f32x4 acc2[4][4] = {};

    for (int ch = 0; ch < 4; ++ch) {
        f32x4 acc1[4][4] = {};
        // ---- h chunk GEMM: h = xb(64x256) @ W1T[ch*256 .. +256][:] ----
        for (int ks = 0; ks < 4; ++ks) {
            __syncthreads();
            const int k0 = ks * 64;
            #pragma unroll
            for (int p = 0; p < 2; ++p) {
                const int idx = tid + p * 256;
                const int r = idx >> 3, s = idx & 7;
                const int row = rowBase + r;
                bf16x8 v = {};
                if (row < MROWS) v = *(const bf16x8*)(xb + (size_t)row * 256 + k0 + s * 8);
                *(bf16x8*)&As[r * 64 + ((s ^ (r & 7)) << 3)] = v;
            }
            #pragma unroll
            for (int p = 0; p < 8; ++p) {
                const int idx = tid + p * 256;
                const int n = idx >> 3, s = idx & 7;
                bf16x8 v = *(const bf16x8*)(BT1 + (size_t)(ch * 256 + n) * 256 + k0 + s * 8);
                *(bf16x8*)&Bs[n * 64 + ((s ^ (n & 7)) << 3)] = v;
            }
            __syncthreads();
            #pragma unroll
            for (int kk = 0; kk < 2; ++kk) {
                bf16x8 aF[4], bF[4];
                const int sl = kk * 4 + rg;
                #pragma unroll
                for (int i = 0; i < 4; ++i) {
                    const int r = i * 16 + lc;
                    aF[i] = *(const bf16x8*)&As[r * 64 + ((sl ^ (r & 7)) << 3)];
                }
                #pragma unroll
                for (int j = 0; j < 4; ++j) {
                    const int n = w * 64 + j * 16 + lc;
                    bF[j] = *(const bf16x8*)&Bs[n * 64 + ((sl ^ (n & 7)) << 3)];
                }
                #pragma unroll
                for (int i = 0; i < 4; ++i)
                    #pragma unroll
                    for (int j = 0; j < 4; ++j)
                        acc1[i][j] = __builtin_amdgcn_mfma_f32_16x16x32_bf16(aF[i], bF[j], acc1[i][j], 0, 0, 0);
            }
        }
        // ---- h -> LDS (relu + bf16), swizzled row-major [64][256] ----
        __syncthreads();
        #pragma unroll
        for (int i = 0; i < 4; ++i)
            #pragma unroll
            for (int r4 = 0; r4 < 4; ++r4) {
                const int hrow = i * 16 + rg * 4 + r4;
                #pragma unroll
                for (int j = 0; j < 4; ++j) {
                    const int hcol = w * 64 + j * 16 + lc;
                    const float t = fmaxf(acc1[i][j][r4] + b1[ch * 256 + hcol], 0.f);
                    Hs[hrow * 256 + ((((hcol >> 3) ^ (hrow & 7))) << 3) + (hcol & 7)] = f2bf(t);
                }
            }
        // ---- out chunk GEMM: acc2 += h(64x256) @ W2T[:, ch*256 .. +256] ----
        for (int ks = 0; ks < 4; ++ks) {
            __syncthreads();
            #pragma unroll
            for (int p = 0; p < 8; ++p) {
                const int idx = tid + p * 256;
                const int n = idx >> 3, s = idx & 7;
                bf16x8 v = *(const bf16x8*)(BT2 + (size_t)n * 1024 + ch * 256 + ks * 64 + s * 8);
                *(bf16x8*)&Bs[n * 64 + ((s ^ (n & 7)) << 3)] = v;
            }
            __syncthreads();
            #pragma unroll
            for (int kk = 0; kk < 2; ++kk) {
                bf16x8 aF[4], bF[4];
                #pragma unroll
                for (int i = 0; i < 4; ++i) {
                    const int r = i * 16 + lc;
                    const int sl = ks * 8 + kk * 4 + rg;   // slot within 32-slot row
                    aF[i] = *(const bf16x8*)&Hs[r * 256 + ((sl ^ (r & 7)) << 3)];
                }
                const int slb = kk * 4 + rg;
                #pragma unroll
                for (int j = 0; j < 4; ++j) {
                    const int n = w * 64 + j * 16 + lc;
                    bF[j] = *(const bf16x8*)&Bs[n * 64 + ((slb ^ (n & 7)) << 3)];
                }
                #pragma unroll
                for (int i = 0; i < 4; ++i)
                    #pragma unroll
                    for (int j = 0; j < 4; ++j)
                        acc2[i][j] = __builtin_amdgcn_mfma_f32_16x16x32_bf16(aF[i], bF[j], acc2[i][j], 0, 0, 0);
            }
        }
    }
    // ---- epilogue: + b2 + resid(xb) + LN2 -> fp32 out ----
    #pragma unroll
    for (int i = 0; i < 4; ++i)
        #pragma unroll
        for (int r4 = 0; r4 < 4; ++r4) {
            const int row = rowBase + i * 16 + rg * 4 + r4;
            float s = 0.f, q = 0.f;
            #pragma unroll
            for (int j = 0; j < 4; ++j) {
                const int col = w * 64 + j * 16 + lc;
                float t = acc2[i][j][r4] + b2[col];
                if (row < MROWS) t += bf2f(xb[(size_t)row * 256 + col]);
                acc2[i][j][r4] = t;
                s += t; q += t * t;
            }
            #pragma unroll
            for (int o = 1; o <= 8; o <<= 1) { s += __shfl_xor(s, o); q += __shfl_xor(q, o); }
            if (lc == 0) { ps[i * 16 + rg * 4 + r4][w] = s; pq[i * 16 + rg * 4 + r4][w] = q; }
        }
    __syncthreads();
    if (tid < 64) {
        const float s = ps[tid][0] + ps[tid][1] + ps[tid][2] + ps[tid][3];
        const float q = pq[tid][0] + pq[tid][1] + pq[tid][2] + pq[tid][3];
        const float m = s * (1.f / 256.f);
        mu_s[tid] = m;
        rs_s[tid] = rsqrtf(q * (1.f / 256.f) - m * m + 1e-5f);
    }
    __syncthreads();
    #pragma unroll
    for (int i = 0; i < 4; ++i)
        #pragma unroll
        for (int r4 = 0; r4 < 4; ++r4) {
            const int rl = i * 16 + rg * 4 + r4;
            const int row = rowBase + rl;
            if (row >= MROWS) continue;
            const float m = mu_s[rl], r = rs_s[rl];
            #pragma unroll
            for (int j = 0; j < 4; ++j) {
                const int col = w * 64 + j * 16 + lc;
                out[(size_t)row * 256 + col] = (acc2[i][j][r4] - m) * r * g[col] + be[col];
            }
        }
}

// ---------------- deformable sampling (bf16 value, bf16 out) ----------------
#define QB 4
__global__ __launch_bounds__(256) void sample_k(
    const unsigned short* __restrict__ value, const float* __restrict__ loc_i,
    const float* __restrict__ attn_i, unsigned short* __restrict__ samp_o)
{
    constexpr int LVL_H[4] = {100, 50, 25, 13};
    constexpr int LVL_W[4] = {152, 76, 38, 19};
    constexpr int LVL_S[4] = {0, 15200, 19000, 19950};
    const int tid = threadIdx.x;
    const int rowBase = blockIdx.x * QB;

    __shared__ int   sIdx[QB][128][4];
    __shared__ float sW[QB][128][4];

    #pragma unroll
    for (int it = 0; it < 2; ++it) {
        const int item = tid + it * 256;
        const int qs = item >> 7;
        const int t  = item & 127;
        const int row = rowBase + qs;
        if (row < MROWS) {
            const int lv = (t >> 3) & 3;
            const int n = (row >= LQ) ? 1 : 0;
            const int H = LVL_H[lv], W = LVL_W[lv];
            const float lx = loc_i[(size_t)row * 256 + t * 2 + 0];
            const float ly = loc_i[(size_t)row * 256 + t * 2 + 1];
            const float a  = attn_i[(size_t)row * 128 + t];
            const float x = lx * (float)W - 0.5f;
            const float y = ly * (float)H - 0.5f;
            const float x0f = floorf(x), y0f = floorf(y);
            const float wx = x - x0f, wy = y - y0f;
            const int x0 = (int)x0f, y0 = (int)y0f;
            const int base = n * LQ + LVL_S[lv];
            #pragma unroll
            for (int nb = 0; nb < 4; ++nb) {
                const int dx = nb & 1, dy = nb >> 1;
                const int xi = x0 + dx, yi = y0 + dy;
                const bool valid = (xi >= 0) & (xi < W) & (yi >= 0) & (yi < H);
                const float wgt = (dx ? wx : 1.f - wx) * (dy ? wy : 1.f - wy) * a;
                sW[qs][t][nb]   = valid ? wgt : 0.f;
                sIdx[qs][t][nb] = valid ? (base + yi * W + xi) : 0;
            }
        }
    }
    __syncthreads();

    const int qs = tid >> 6;
    const int c4 = tid & 63;
    const int row = rowBase + qs;
    if (row >= MROWS) return;
    const int m = c4 >> 4;
    const unsigned short* vbase = value + c4 * 4;
    const int tbase = m * 32;

    float4 acc = {0.f, 0.f, 0.f, 0.f};
    #pragma unroll
    for (int t = 0; t < 32; ++t) {
        #pragma unroll
        for (int nb = 0; nb < 4; ++nb) {
            const float wgt = sW[qs][tbase + t][nb];
            if (wgt != 0.f) {
                const int idx = sIdx[qs][tbase + t][nb];
                const ushort4 u = *(const ushort4*)(vbase + (size_t)idx * 256);
                acc.x += wgt * bf2f(u.x);
                acc.y += wgt * bf2f(u.y);
                acc.z += wgt * bf2f(u.z);
                acc.w += wgt * bf2f(u.w);
            }
        }
    }
    *(ushort4*)(samp_o + (size_t)row * 256 + c4 * 4) =
        make_ushort4(f2bf(acc.x), f2bf(acc.y), f2bf(acc.z), f2bf(acc.w));
}

extern "C" void kernel_launch(void* const* d_in, const int* in_sizes, int n_in,
                              void* d_out, int out_size, void* d_ws, size_t ws_size,
                              hipStream_t stream)
{
    const float* src_feat = (const float*)d_in[0];
    const float* refpts   = (const float*)d_in[1];
    const float* key_feat = (const float*)d_in[2];
    const float* W_off  = (const float*)d_in[5];
    const float* b_off  = (const float*)d_in[6];
    const float* W_attn = (const float*)d_in[7];
    const float* b_attn = (const float*)d_in[8];
    const float* W_val  = (const float*)d_in[9];
    const float* b_val  = (const float*)d_in[10];
    const float* W_out  = (const float*)d_in[11];
    const float* b_out  = (const float*)d_in[12];
    const float* W1  = (const float*)d_in[13];
    const float* b1  = (const float*)d_in[14];
    const float* W2  = (const float*)d_in[15];
    const float* b2  = (const float*)d_in[16];
    const float* g1  = (const float*)d_in[17];
    const float* be1 = (const float*)d_in[18];
    const float* g2  = (const float*)d_in[19];
    const float* be2 = (const float*)d_in[20];

    float* out = (float*)d_out;
    float* x_out    = out;                           // (M,256) fp32
    float* loc_out  = out + MR256;                   // (M,256) fp32
    float* attn_out = out + 2 * MR256;               // (M,128) fp32

    char* ws = (char*)d_ws;
    unsigned short* BTv   = (unsigned short*)(ws + 0);
    unsigned short* BTo   = (unsigned short*)(ws + 131072);
    unsigned short* BTa   = (unsigned short*)(ws + 262144);
    unsigned short* BTu   = (unsigned short*)(ws + 393216);
    unsigned short* BT1   = (unsigned short*)(ws + 524288);
    unsigned short* BT2   = (unsigned short*)(ws + 1048576);
    float*          battn = (float*)(ws + 1572864);
    unsigned short* srcb  = (unsigned short*)(ws + 2097152);            // -> xb later
    unsigned short* keyb  = (unsigned short*)(ws + 2097152 + MR256*2);  // -> value in-place
    unsigned short* samp  = (unsigned short*)(ws + 2097152 + MR256*4);
    unsigned short* xb    = srcb;
    unsigned short* value = keyb;

    const int RB = (MROWS + 63) / 64;   // 632

    prep_k<<<1024, 256, 0, stream>>>(src_feat, key_feat, W_val, W_off, W_attn, W_out,
                                     W1, W2, b_attn,
                                     srcb, keyb, BTv, BTo, BTa, BTu, BT1, BT2, battn);
    // value = key@Wv+bv (bf16, in-place over keyb)
    gemm_k<EP_VAL><<<RB, 256, 0, stream>>>(keyb, BTv, b_val, nullptr, nullptr, nullptr, value);
    // loc = ref + (src@Wo+bo)/norm  -> d_out
    gemm_k<EP_LOC><<<RB, 256, 0, stream>>>(srcb, BTo, b_off, refpts, nullptr, nullptr, loc_out);
    // attn = softmax(src@Wa+ba) -> d_out
    gemm_k<EP_ATTN><<<RB, 256, 0, stream>>>(srcb, BTa, battn, nullptr, nullptr, nullptr, attn_out);
    // deformable sampling -> bf16 samp
    sample_k<<<(MROWS + QB - 1) / QB, 256, 0, stream>>>(value, loc_out, attn_out, samp);
    // x = LN1(src + samp@Wu+bu) -> bf16 xb
    gemm_k<EP_LN><<<RB, 256, 0, stream>>>(samp, BTu, b_out, src_feat, g1, be1, xb);
    // x2 = LN2(x + FFN(x)) -> fp32 d_out
    ffn_k<<<RB, 256, 0, stream>>>(xb, BT1, b1, BT2, b2, g2, be2, x_out);
}

// Round 4
// 450.474 us; speedup vs baseline: 4.7869x; 1.3689x over previous
//
#include <hip/hip_runtime.h>
#include <hip/hip_bf16.h>

#define LQ 20197
#define NBATCH 2
#define MROWS 40394
#define MR256 ((size_t)MROWS * 256)

typedef __attribute__((ext_vector_type(8))) short bf16x8;
typedef __attribute__((ext_vector_type(4))) float f32x4;

__device__ __forceinline__ unsigned short f2bf(float f) {
    unsigned u = __float_as_uint(f);
    return (unsigned short)((u + 0x7fff + ((u >> 16) & 1)) >> 16);   // RNE
}
__device__ __forceinline__ float bf2f(unsigned short b) {
    return __uint_as_float((unsigned)b << 16);
}

// ---------------- prep: weight transposes (bf16) ----------------
__global__ __launch_bounds__(256) void prep_w_k(
    const float* __restrict__ Wv, const float* __restrict__ Wo,
    const float* __restrict__ Wa, const float* __restrict__ Wu,
    const float* __restrict__ W1, const float* __restrict__ W2,
    const float* __restrict__ ba,
    unsigned short* __restrict__ BTv, unsigned short* __restrict__ BTo,
    unsigned short* __restrict__ BTa, unsigned short* __restrict__ BTu,
    unsigned short* __restrict__ BT1, unsigned short* __restrict__ BT2,
    float* __restrict__ battn)
{
    const size_t id0 = (size_t)blockIdx.x * blockDim.x + threadIdx.x;
    const size_t stride = (size_t)gridDim.x * blockDim.x;
    for (size_t i = id0; i < 65536; i += stride) {
        const int n = (int)(i >> 8), k = (int)(i & 255);
        BTv[i] = f2bf(Wv[k * 256 + n]);
        BTo[i] = f2bf(Wo[k * 256 + n]);
        BTu[i] = f2bf(Wu[k * 256 + n]);
        BTa[i] = (n < 128) ? f2bf(Wa[k * 128 + n]) : (unsigned short)0;
    }
    for (size_t i = id0; i < 262144; i += stride) {
        const int n = (int)(i >> 8), k = (int)(i & 255);      // BT1 [1024][256]
        BT1[i] = f2bf(W1[(size_t)k * 1024 + n]);
        const int n2 = (int)(i >> 10), k2 = (int)(i & 1023);  // BT2 [256][1024]
        BT2[i] = f2bf(W2[(size_t)k2 * 256 + n2]);
    }
    if (id0 < 256) battn[id0] = (id0 < 128) ? ba[id0] : 0.f;
}

// ---------------- MFMA GEMM: 64x256 tile, K=256, 4 waves, XOR-swizzled LDS ----------------
enum { EP_VAL = 0, EP_LOC = 1, EP_ATTN = 2, EP_LN = 3, EP_FFN1 = 4 };

template<int EP, bool AF32>
__global__ __launch_bounds__(256) void gemm_k(
    const void* __restrict__ Ap, const unsigned short* __restrict__ BT,
    const float* __restrict__ bias, const float* __restrict__ aux,
    const float* __restrict__ g, const float* __restrict__ be,
    void* outp, void* outp2)
{
    __shared__ __align__(16) unsigned short As[64 * 64];
    __shared__ __align__(16) unsigned short Bs[256 * 64];
    __shared__ float ps[64][4], pq[64][4];
    __shared__ float mu_s[64], rs_s[64];

    const int tid = threadIdx.x;
    const int l = tid & 63, w = tid >> 6;
    const int lc = l & 15, rg = l >> 4;
    const int rowBase = blockIdx.x * 64;
    const unsigned short* BTb = BT + (size_t)blockIdx.y * 65536;   // 256-col panel

    f32x4 acc[4][4] = {};

    for (int k0 = 0; k0 < 256; k0 += 64) {
        if (k0) __syncthreads();
        #pragma unroll
        for (int p = 0; p < 2; ++p) {           // stage A 64x64 (convert fp32->bf16 if needed)
            const int idx = tid + p * 256;
            const int r = idx >> 3, s = idx & 7;
            const int row = rowBase + r;
            bf16x8 v = {};
            if (AF32) {
                if (row < MROWS) {
                    const float* A = (const float*)Ap;
                    const float4 v0 = *(const float4*)(A + (size_t)row * 256 + k0 + s * 8);
                    const float4 v1 = *(const float4*)(A + (size_t)row * 256 + k0 + s * 8 + 4);
                    v[0] = (short)f2bf(v0.x); v[1] = (short)f2bf(v0.y);
                    v[2] = (short)f2bf(v0.z); v[3] = (short)f2bf(v0.w);
                    v[4] = (short)f2bf(v1.x); v[5] = (short)f2bf(v1.y);
                    v[6] = (short)f2bf(v1.z); v[7] = (short)f2bf(v1.w);
                }
            } else {
                if (row < MROWS)
                    v = *(const bf16x8*)((const unsigned short*)Ap + (size_t)row * 256 + k0 + s * 8);
            }
            *(bf16x8*)&As[r * 64 + ((s ^ (r & 7)) << 3)] = v;
        }
        #pragma unroll
        for (int p = 0; p < 8; ++p) {           // stage B 256x64
            const int idx = tid + p * 256;
            const int n = idx >> 3, s = idx & 7;
            bf16x8 v = *(const bf16x8*)(BTb + (size_t)n * 256 + k0 + s * 8);
            *(bf16x8*)&Bs[n * 64 + ((s ^ (n & 7)) << 3)] = v;
        }
        __syncthreads();
        #pragma unroll
        for (int kk = 0; kk < 2; ++kk) {
            bf16x8 aF[4], bF[4];
            const int sl = kk * 4 + rg;
            #pragma unroll
            for (int i = 0; i < 4; ++i) {
                const int r = i * 16 + lc;
                aF[i] = *(const bf16x8*)&As[r * 64 + ((sl ^ (r & 7)) << 3)];
            }
            #pragma unroll
            for (int j = 0; j < 4; ++j) {
                const int n = w * 64 + j * 16 + lc;
                bF[j] = *(const bf16x8*)&Bs[n * 64 + ((sl ^ (n & 7)) << 3)];
            }
            #pragma unroll
            for (int i = 0; i < 4; ++i)
                #pragma unroll
                for (int j = 0; j < 4; ++j)
                    acc[i][j] = __builtin_amdgcn_mfma_f32_16x16x32_bf16(aF[i], bF[j], acc[i][j], 0, 0, 0);
        }
    }

    if (EP == EP_VAL) {
        unsigned short* out = (unsigned short*)outp;
        #pragma unroll
        for (int i = 0; i < 4; ++i)
            #pragma unroll
            for (int r4 = 0; r4 < 4; ++r4) {
                const int row = rowBase + i * 16 + rg * 4 + r4;
                if (row >= MROWS) continue;
                #pragma unroll
                for (int j = 0; j < 4; ++j) {
                    const int col = w * 64 + j * 16 + lc;
                    out[(size_t)row * 256 + col] = f2bf(acc[i][j][r4] + bias[col]);
                }
            }
    } else if (EP == EP_FFN1) {
        unsigned short* h0 = (unsigned short*)outp;
        unsigned short* h1 = (unsigned short*)outp2;
        unsigned short* hb = (blockIdx.y < 2) ? h0 : h1;
        const int cbase = (blockIdx.y & 1) * 256;
        #pragma unroll
        for (int i = 0; i < 4; ++i)
            #pragma unroll
            for (int r4 = 0; r4 < 4; ++r4) {
                const int row = rowBase + i * 16 + rg * 4 + r4;
                if (row >= MROWS) continue;
                #pragma unroll
                for (int j = 0; j < 4; ++j) {
                    const int col = w * 64 + j * 16 + lc;
                    const float t = fmaxf(acc[i][j][r4] + bias[blockIdx.y * 256 + col], 0.f);
                    hb[(size_t)row * 512 + cbase + col] = f2bf(t);
                }
            }
    } else if (EP == EP_LOC) {
        float* out = (float*)outp;
        const float INV[8] = {1.f/152, 1.f/100, 1.f/76, 1.f/50, 1.f/38, 1.f/25, 1.f/19, 1.f/13};
        #pragma unroll
        for (int i = 0; i < 4; ++i)
            #pragma unroll
            for (int r4 = 0; r4 < 4; ++r4) {
                const int row = rowBase + i * 16 + rg * 4 + r4;
                if (row >= MROWS) continue;
                #pragma unroll
                for (int j = 0; j < 4; ++j) {
                    const int col = w * 64 + j * 16 + lc;
                    const int lvl = (col >> 4) & 3, xy = col & 1;
                    const float off = acc[i][j][r4] + bias[col];
                    const float ref = aux[(size_t)row * 8 + lvl * 2 + xy];
                    out[(size_t)row * 256 + col] = ref + off * INV[lvl * 2 + xy];
                }
            }
    } else if (EP == EP_ATTN) {
        if (w >= 2) return;                     // cols 128-255 are padding
        float* out = (float*)outp;
        #pragma unroll
        for (int i = 0; i < 4; ++i)
            #pragma unroll
            for (int r4 = 0; r4 < 4; ++r4) {
                const int row = rowBase + i * 16 + rg * 4 + r4;
                float v[4];
                #pragma unroll
                for (int j = 0; j < 4; ++j) v[j] = acc[i][j][r4] + bias[w * 64 + j * 16 + lc];
                float mA = fmaxf(v[0], v[1]), mB = fmaxf(v[2], v[3]);
                #pragma unroll
                for (int o = 1; o <= 8; o <<= 1) {
                    mA = fmaxf(mA, __shfl_xor(mA, o));
                    mB = fmaxf(mB, __shfl_xor(mB, o));
                }
                float e[4];
                e[0] = __expf(v[0] - mA); e[1] = __expf(v[1] - mA);
                e[2] = __expf(v[2] - mB); e[3] = __expf(v[3] - mB);
                float sA = e[0] + e[1], sB = e[2] + e[3];
                #pragma unroll
                for (int o = 1; o <= 8; o <<= 1) {
                    sA += __shfl_xor(sA, o);
                    sB += __shfl_xor(sB, o);
                }
                if (row >= MROWS) continue;
                #pragma unroll
                for (int j = 0; j < 4; ++j) {
                    const int col = w * 64 + j * 16 + lc;   // < 128
                    out[(size_t)row * 128 + col] = e[j] / (j < 2 ? sA : sB);
                }
            }
    } else {   // EP_LN: + bias + resid(fp32 aux) + LayerNorm -> bf16 out
        unsigned short* out = (unsigned short*)outp;
        #pragma unroll
        for (int i = 0; i < 4; ++i)
            #pragma unroll
            for (int r4 = 0; r4 < 4; ++r4) {
                const int row = rowBase + i * 16 + rg * 4 + r4;
                float s = 0.f, q = 0.f;
                #pragma unroll
                for (int j = 0; j < 4; ++j) {
                    const int col = w * 64 + j * 16 + lc;
                    float t = acc[i][j][r4] + bias[col];
                    if (row < MROWS) t += aux[(size_t)row * 256 + col];
                    acc[i][j][r4] = t;
                    s += t; q += t * t;
                }
                #pragma unroll
                for (int o = 1; o <= 8; o <<= 1) { s += __shfl_xor(s, o); q += __shfl_xor(q, o); }
                if (lc == 0) { ps[i * 16 + rg * 4 + r4][w] = s; pq[i * 16 + rg * 4 + r4][w] = q; }
            }
        __syncthreads();
        if (tid < 64) {
            const float s = ps[tid][0] + ps[tid][1] + ps[tid][2] + ps[tid][3];
            const float q = pq[tid][0] + pq[tid][1] + pq[tid][2] + pq[tid][3];
            const float m = s * (1.f / 256.f);
            mu_s[tid] = m;
            rs_s[tid] = rsqrtf(q * (1.f / 256.f) - m * m + 1e-5f);
        }
        __syncthreads();
        #pragma unroll
        for (int i = 0; i < 4; ++i)
            #pragma unroll
            for (int r4 = 0; r4 < 4; ++r4) {
                const int rl = i * 16 + rg * 4 + r4;
                const int row = rowBase + rl;
                if (row >= MROWS) continue;
                const float m = mu_s[rl], r = rs_s[rl];
                #pragma unroll
                for (int j = 0; j < 4; ++j) {
                    const int col = w * 64 + j * 16 + lc;
                    out[(size_t)row * 256 + col] = f2bf((acc[i][j][r4] - m) * r * g[col] + be[col]);
                }
            }
    }
}

// ---------------- FFN2: out = LN2(xb + h@W2 + b2), K=1024, h split h0/h1 ----------------
__global__ __launch_bounds__(256) void ffn2_k(
    const unsigned short* __restrict__ h0, const unsigned short* __restrict__ h1,
    const unsigned short* __restrict__ BT2,   // [256][1024]
    const float* __restrict__ bias, const unsigned short* __restrict__ xb,
    const float* __restrict__ g, const float* __restrict__ be,
    float* __restrict__ out)
{
    __shared__ __align__(16) unsigned short As[64 * 64];
    __shared__ __align__(16) unsigned short Bs[256 * 64];
    __shared__ float ps[64][4], pq[64][4];
    __shared__ float mu_s[64], rs_s[64];

    const int tid = threadIdx.x;
    const int l = tid & 63, w = tid >> 6;
    const int lc = l & 15, rg = l >> 4;
    const int rowBase = blockIdx.x * 64;

    f32x4 acc[4][4] = {};

    for (int kc = 0; kc < 16; ++kc) {
        if (kc) __syncthreads();
        const unsigned short* Ab = (kc < 8) ? h0 : h1;
        const int koff = (kc & 7) * 64;
        #pragma unroll
        for (int p = 0; p < 2; ++p) {           // stage A 64x64 from h
            const int idx = tid + p * 256;
            const int r = idx >> 3, s = idx & 7;
            const int row = rowBase + r;
            bf16x8 v = {};
            if (row < MROWS) v = *(const bf16x8*)(Ab + (size_t)row * 512 + koff + s * 8);
            *(bf16x8*)&As[r * 64 + ((s ^ (r & 7)) << 3)] = v;
        }
        #pragma unroll
        for (int p = 0; p < 8; ++p) {           // stage B 256x64
            const int idx = tid + p * 256;
            const int n = idx >> 3, s = idx & 7;
            bf16x8 v = *(const bf16x8*)(BT2 + (size_t)n * 1024 + kc * 64 + s * 8);
            *(bf16x8*)&Bs[n * 64 + ((s ^ (n & 7)) << 3)] = v;
        }
        __syncthreads();
        #pragma unroll
        for (int kk = 0; kk < 2; ++kk) {
            bf16x8 aF[4], bF[4];
            const int sl = kk * 4 + rg;
            #pragma unroll
            for (int i = 0; i < 4; ++i) {
                const int r = i * 16 + lc;
                aF[i] = *(const bf16x8*)&As[r * 64 + ((sl ^ (r & 7)) << 3)];
            }
            #pragma unroll
            for (int j = 0; j < 4; ++j) {
                const int n = w * 64 + j * 16 + lc;
                bF[j] = *(const bf16x8*)&Bs[n * 64 + ((sl ^ (n & 7)) << 3)];
            }
            #pragma unroll
            for (int i = 0; i < 4; ++i)
                #pragma unroll
                for (int j = 0; j < 4; ++j)
                    acc[i][j] = __builtin_amdgcn_mfma_f32_16x16x32_bf16(aF[i], bF[j], acc[i][j], 0, 0, 0);
        }
    }

    // epilogue: + b2 + resid(xb bf16) + LN2 -> fp32
    #pragma unroll
    for (int i = 0; i < 4; ++i)
        #pragma unroll
        for (int r4 = 0; r4 < 4; ++r4) {
            const int row = rowBase + i * 16 + rg * 4 + r4;
            float s = 0.f, q = 0.f;
            #pragma unroll
            for (int j = 0; j < 4; ++j) {
                const int col = w * 64 + j * 16 + lc;
                float t = acc[i][j][r4] + bias[col];
                if (row < MROWS) t += bf2f(xb[(size_t)row * 256 + col]);
                acc[i][j][r4] = t;
                s += t; q += t * t;
            }
            #pragma unroll
            for (int o = 1; o <= 8; o <<= 1) { s += __shfl_xor(s, o); q += __shfl_xor(q, o); }
            if (lc == 0) { ps[i * 16 + rg * 4 + r4][w] = s; pq[i * 16 + rg * 4 + r4][w] = q; }
        }
    __syncthreads();
    if (tid < 64) {
        const float s = ps[tid][0] + ps[tid][1] + ps[tid][2] + ps[tid][3];
        const float q = pq[tid][0] + pq[tid][1] + pq[tid][2] + pq[tid][3];
        const float m = s * (1.f / 256.f);
        mu_s[tid] = m;
        rs_s[tid] = rsqrtf(q * (1.f / 256.f) - m * m + 1e-5f);
    }
    __syncthreads();
    #pragma unroll
    for (int i = 0; i < 4; ++i)
        #pragma unroll
        for (int r4 = 0; r4 < 4; ++r4) {
            const int rl = i * 16 + rg * 4 + r4;
            const int row = rowBase + rl;
            if (row >= MROWS) continue;
            const float m = mu_s[rl], r = rs_s[rl];
            #pragma unroll
            for (int j = 0; j < 4; ++j) {
                const int col = w * 64 + j * 16 + lc;
                out[(size_t)row * 256 + col] = (acc[i][j][r4] - m) * r * g[col] + be[col];
            }
        }
}

// ---------------- deformable sampling (bf16 value, bf16 out), XCD-chunked ----------------
#define QB 4
__global__ __launch_bounds__(256) void sample_k(
    const unsigned short* __restrict__ value, const float* __restrict__ loc_i,
    const float* __restrict__ attn_i, unsigned short* __restrict__ samp_o)
{
    constexpr int LVL_H[4] = {100, 50, 25, 13};
    constexpr int LVL_W[4] = {152, 76, 38, 19};
    constexpr int LVL_S[4] = {0, 15200, 19000, 19950};
    const int tid = threadIdx.x;

    // bijective XCD-chunked swizzle (m204): consecutive work chunks stay on one XCD's L2
    const int nwg = gridDim.x;
    const int bid = blockIdx.x;
    const int xcd = bid & 7, lid = bid >> 3;
    const int qq = nwg >> 3, rr = nwg & 7;
    const int sw = (xcd < rr ? xcd * (qq + 1) : rr * (qq + 1) + (xcd - rr) * qq) + lid;
    const int rowBase = sw * QB;

    __shared__ int   sIdx[QB][128][4];
    __shared__ float sW[QB][128][4];

    #pragma unroll
    for (int it = 0; it < 2; ++it) {
        const int item = tid + it * 256;
        const int qs = item >> 7;
        const int t  = item & 127;
        const int row = rowBase + qs;
        if (row < MROWS) {
            const int lv = (t >> 3) & 3;
            const int n = (row >= LQ) ? 1 : 0;
            const int H = LVL_H[lv], W = LVL_W[lv];
            const float lx = loc_i[(size_t)row * 256 + t * 2 + 0];
            const float ly = loc_i[(size_t)row * 256 + t * 2 + 1];
            const float a  = attn_i[(size_t)row * 128 + t];
            const float x = lx * (float)W - 0.5f;
            const float y = ly * (float)H - 0.5f;
            const float x0f = floorf(x), y0f = floorf(y);
            const float wx = x - x0f, wy = y - y0f;
            const int x0 = (int)x0f, y0 = (int)y0f;
            const int base = n * LQ + LVL_S[lv];
            #pragma unroll
            for (int nb = 0; nb < 4; ++nb) {
                const int dx = nb & 1, dy = nb >> 1;
                const int xi = x0 + dx, yi = y0 + dy;
                const bool valid = (xi >= 0) & (xi < W) & (yi >= 0) & (yi < H);
                const float wgt = (dx ? wx : 1.f - wx) * (dy ? wy : 1.f - wy) * a;
                sW[qs][t][nb]   = valid ? wgt : 0.f;
                sIdx[qs][t][nb] = valid ? (base + yi * W + xi) : 0;
            }
        }
    }
    __syncthreads();

    const int qs = tid >> 6;
    const int c4 = tid & 63;
    const int row = rowBase + qs;
    if (row >= MROWS) return;
    const int m = c4 >> 4;
    const unsigned short* vbase = value + c4 * 4;
    const int tbase = m * 32;

    float4 acc = {0.f, 0.f, 0.f, 0.f};
    #pragma unroll
    for (int t = 0; t < 32; ++t) {
        #pragma unroll
        for (int nb = 0; nb < 4; ++nb) {
            const float wgt = sW[qs][tbase + t][nb];
            if (wgt != 0.f) {
                const int idx = sIdx[qs][tbase + t][nb];
                const ushort4 u = *(const ushort4*)(vbase + (size_t)idx * 256);
                acc.x += wgt * bf2f(u.x);
                acc.y += wgt * bf2f(u.y);
                acc.z += wgt * bf2f(u.z);
                acc.w += wgt * bf2f(u.w);
            }
        }
    }
    *(ushort4*)(samp_o + (size_t)row * 256 + c4 * 4) =
        make_ushort4(f2bf(acc.x), f2bf(acc.y), f2bf(acc.z), f2bf(acc.w));
}

extern "C" void kernel_launch(void* const* d_in, const int* in_sizes, int n_in,
                              void* d_out, int out_size, void* d_ws, size_t ws_size,
                              hipStream_t stream)
{
    const float* src_feat = (const float*)d_in[0];
    const float* refpts   = (const float*)d_in[1];
    const float* key_feat = (const float*)d_in[2];
    const float* W_off  = (const float*)d_in[5];
    const float* b_off  = (const float*)d_in[6];
    const float* W_attn = (const float*)d_in[7];
    const float* b_attn = (const float*)d_in[8];
    const float* W_val  = (const float*)d_in[9];
    const float* b_val  = (const float*)d_in[10];
    const float* W_out  = (const float*)d_in[11];
    const float* b_out  = (const float*)d_in[12];
    const float* W1  = (const float*)d_in[13];
    const float* b1  = (const float*)d_in[14];
    const float* W2  = (const float*)d_in[15];
    const float* b2  = (const float*)d_in[16];
    const float* g1  = (const float*)d_in[17];
    const float* be1 = (const float*)d_in[18];
    const float* g2  = (const float*)d_in[19];
    const float* be2 = (const float*)d_in[20];

    float* out = (float*)d_out;
    float* x_out    = out;                           // (M,256) fp32
    float* loc_out  = out + MR256;                   // (M,256) fp32
    float* attn_out = out + 2 * MR256;               // (M,128) fp32

    char* ws = (char*)d_ws;
    unsigned short* BTv   = (unsigned short*)(ws + 0);
    unsigned short* BTo   = (unsigned short*)(ws + 131072);
    unsigned short* BTa   = (unsigned short*)(ws + 262144);
    unsigned short* BTu   = (unsigned short*)(ws + 393216);
    unsigned short* BT1   = (unsigned short*)(ws + 524288);
    unsigned short* BT2   = (unsigned short*)(ws + 1048576);
    float*          battn = (float*)(ws + 1572864);
    // data regions (bytes): value [2M, 2M+20.68M), samp next, xb next; h0 overlays value+samp
    unsigned short* value = (unsigned short*)(ws + 2097152);
    unsigned short* samp  = (unsigned short*)(ws + 2097152 + MR256 * 2);
    unsigned short* xb    = (unsigned short*)(ws + 2097152 + MR256 * 4);
    unsigned short* h0    = value;                       // [M][512] bf16 = exactly value+samp
    unsigned short* h1    = (unsigned short*)x_out;      // [M][512] bf16 = exactly x_out bytes

    const int RB = (MROWS + 63) / 64;   // 632

    prep_w_k<<<512, 256, 0, stream>>>(W_val, W_off, W_attn, W_out, W1, W2, b_attn,
                                      BTv, BTo, BTa, BTu, BT1, BT2, battn);
    // value = key@Wv+bv (bf16)
    gemm_k<EP_VAL, true><<<dim3(RB, 1), 256, 0, stream>>>(key_feat, BTv, b_val, nullptr, nullptr, nullptr, value, nullptr);
    // loc = ref + (src@Wo+bo)/norm  -> d_out
    gemm_k<EP_LOC, true><<<dim3(RB, 1), 256, 0, stream>>>(src_feat, BTo, b_off, refpts, nullptr, nullptr, loc_out, nullptr);
    // attn = softmax(src@Wa+ba) -> d_out
    gemm_k<EP_ATTN, true><<<dim3(RB, 1), 256, 0, stream>>>(src_feat, BTa, battn, nullptr, nullptr, nullptr, attn_out, nullptr);
    // deformable sampling -> bf16 samp
    sample_k<<<(MROWS + QB - 1) / QB, 256, 0, stream>>>(value, loc_out, attn_out, samp);
    // x = LN1(src + samp@Wu+bu) -> bf16 xb
    gemm_k<EP_LN, false><<<dim3(RB, 1), 256, 0, stream>>>(samp, BTu, b_out, src_feat, g1, be1, xb, nullptr);
    // h = relu(x@W1+b1) -> bf16, split h0 (cols 0-511) / h1 (cols 512-1023)
    gemm_k<EP_FFN1, false><<<dim3(RB, 4), 256, 0, stream>>>(xb, BT1, b1, nullptr, nullptr, nullptr, h0, h1);
    // x2 = LN2(x + h@W2+b2) -> fp32 d_out
    ffn2_k<<<dim3(RB, 1), 256, 0, stream>>>(h0, h1, BT2, b2, xb, g2, be2, x_out);
}

// Round 5
// 345.545 us; speedup vs baseline: 6.2404x; 1.3037x over previous
//
#include <hip/hip_runtime.h>
#include <hip/hip_bf16.h>

#define LQ 20197
#define NBATCH 2
#define MROWS 40394
#define MR256 ((size_t)MROWS * 256)

typedef __attribute__((ext_vector_type(8))) short bf16x8;
typedef __attribute__((ext_vector_type(4))) float f32x4;
typedef __attribute__((ext_vector_type(2))) float f32x2;

__device__ __forceinline__ unsigned short f2bf(float f) {
    unsigned u = __float_as_uint(f);
    return (unsigned short)((u + 0x7fff + ((u >> 16) & 1)) >> 16);   // RNE
}
__device__ __forceinline__ float bf2f(unsigned short b) {
    return __uint_as_float((unsigned)b << 16);
}

// ---------------- prep: weight transposes (bf16) ----------------
__global__ __launch_bounds__(256) void prep_w_k(
    const float* __restrict__ Wv, const float* __restrict__ Wo,
    const float* __restrict__ Wa, const float* __restrict__ Wu,
    const float* __restrict__ W1, const float* __restrict__ W2,
    const float* __restrict__ ba,
    unsigned short* __restrict__ BTv, unsigned short* __restrict__ BTo,
    unsigned short* __restrict__ BTa, unsigned short* __restrict__ BTu,
    unsigned short* __restrict__ BT1, unsigned short* __restrict__ BT2,
    float* __restrict__ battn)
{
    const size_t id0 = (size_t)blockIdx.x * blockDim.x + threadIdx.x;
    const size_t stride = (size_t)gridDim.x * blockDim.x;
    for (size_t i = id0; i < 65536; i += stride) {
        const int n = (int)(i >> 8), k = (int)(i & 255);
        BTv[i] = f2bf(Wv[k * 256 + n]);
        BTo[i] = f2bf(Wo[k * 256 + n]);
        BTu[i] = f2bf(Wu[k * 256 + n]);
        BTa[i] = (n < 128) ? f2bf(Wa[k * 128 + n]) : (unsigned short)0;
    }
    for (size_t i = id0; i < 262144; i += stride) {
        const int n = (int)(i >> 8), k = (int)(i & 255);      // BT1 [1024][256]
        BT1[i] = f2bf(W1[(size_t)k * 1024 + n]);
        const int n2 = (int)(i >> 10), k2 = (int)(i & 1023);  // BT2 [256][1024]
        BT2[i] = f2bf(W2[(size_t)k2 * 256 + n2]);
    }
    if (id0 < 256) battn[id0] = (id0 < 128) ? ba[id0] : 0.f;
}

// ---------------- MFMA GEMM: 64x256 tile, K=256, 4 waves, XOR-swizzled LDS ----------------
enum { EP_VAL = 0, EP_LOC = 1, EP_ATTN = 2, EP_LN = 3, EP_FFN1 = 4 };

template<int EP, bool AF32>
__global__ __launch_bounds__(256) void gemm_k(
    const void* __restrict__ Ap, const unsigned short* __restrict__ BT,
    const float* __restrict__ bias, const float* __restrict__ aux,
    const float* __restrict__ g, const float* __restrict__ be,
    void* outp, void* outp2)
{
    __shared__ __align__(16) unsigned short As[64 * 64];
    __shared__ __align__(16) unsigned short Bs[256 * 64];
    __shared__ float ps[64][4], pq[64][4];
    __shared__ float mu_s[64], rs_s[64];

    const int tid = threadIdx.x;
    const int l = tid & 63, w = tid >> 6;
    const int lc = l & 15, rg = l >> 4;
    const int rowBase = blockIdx.x * 64;
    const unsigned short* BTb = BT + (size_t)blockIdx.y * 65536;   // 256-col panel

    f32x4 acc[4][4] = {};

    for (int k0 = 0; k0 < 256; k0 += 64) {
        if (k0) __syncthreads();
        #pragma unroll
        for (int p = 0; p < 2; ++p) {           // stage A 64x64 (convert fp32->bf16 if needed)
            const int idx = tid + p * 256;
            const int r = idx >> 3, s = idx & 7;
            const int row = rowBase + r;
            bf16x8 v = {};
            if (AF32) {
                if (row < MROWS) {
                    const float* A = (const float*)Ap;
                    const float4 v0 = *(const float4*)(A + (size_t)row * 256 + k0 + s * 8);
                    const float4 v1 = *(const float4*)(A + (size_t)row * 256 + k0 + s * 8 + 4);
                    v[0] = (short)f2bf(v0.x); v[1] = (short)f2bf(v0.y);
                    v[2] = (short)f2bf(v0.z); v[3] = (short)f2bf(v0.w);
                    v[4] = (short)f2bf(v1.x); v[5] = (short)f2bf(v1.y);
                    v[6] = (short)f2bf(v1.z); v[7] = (short)f2bf(v1.w);
                }
            } else {
                if (row < MROWS)
                    v = *(const bf16x8*)((const unsigned short*)Ap + (size_t)row * 256 + k0 + s * 8);
            }
            *(bf16x8*)&As[r * 64 + ((s ^ (r & 7)) << 3)] = v;
        }
        #pragma unroll
        for (int p = 0; p < 8; ++p) {           // stage B 256x64
            const int idx = tid + p * 256;
            const int n = idx >> 3, s = idx & 7;
            bf16x8 v = *(const bf16x8*)(BTb + (size_t)n * 256 + k0 + s * 8);
            *(bf16x8*)&Bs[n * 64 + ((s ^ (n & 7)) << 3)] = v;
        }
        __syncthreads();
        #pragma unroll
        for (int kk = 0; kk < 2; ++kk) {
            bf16x8 aF[4], bF[4];
            const int sl = kk * 4 + rg;
            #pragma unroll
            for (int i = 0; i < 4; ++i) {
                const int r = i * 16 + lc;
                aF[i] = *(const bf16x8*)&As[r * 64 + ((sl ^ (r & 7)) << 3)];
            }
            #pragma unroll
            for (int j = 0; j < 4; ++j) {
                const int n = w * 64 + j * 16 + lc;
                bF[j] = *(const bf16x8*)&Bs[n * 64 + ((sl ^ (n & 7)) << 3)];
            }
            #pragma unroll
            for (int i = 0; i < 4; ++i)
                #pragma unroll
                for (int j = 0; j < 4; ++j)
                    acc[i][j] = __builtin_amdgcn_mfma_f32_16x16x32_bf16(aF[i], bF[j], acc[i][j], 0, 0, 0);
        }
    }

    if (EP == EP_VAL) {
        unsigned short* out = (unsigned short*)outp;
        #pragma unroll
        for (int i = 0; i < 4; ++i)
            #pragma unroll
            for (int r4 = 0; r4 < 4; ++r4) {
                const int row = rowBase + i * 16 + rg * 4 + r4;
                if (row >= MROWS) continue;
                #pragma unroll
                for (int j = 0; j < 4; ++j) {
                    const int col = w * 64 + j * 16 + lc;
                    out[(size_t)row * 256 + col] = f2bf(acc[i][j][r4] + bias[col]);
                }
            }
    } else if (EP == EP_FFN1) {
        unsigned short* h0 = (unsigned short*)outp;
        unsigned short* h1 = (unsigned short*)outp2;
        unsigned short* hb = (blockIdx.y < 2) ? h0 : h1;
        const int cbase = (blockIdx.y & 1) * 256;
        #pragma unroll
        for (int i = 0; i < 4; ++i)
            #pragma unroll
            for (int r4 = 0; r4 < 4; ++r4) {
                const int row = rowBase + i * 16 + rg * 4 + r4;
                if (row >= MROWS) continue;
                #pragma unroll
                for (int j = 0; j < 4; ++j) {
                    const int col = w * 64 + j * 16 + lc;
                    const float t = fmaxf(acc[i][j][r4] + bias[blockIdx.y * 256 + col], 0.f);
                    hb[(size_t)row * 512 + cbase + col] = f2bf(t);
                }
            }
    } else if (EP == EP_LOC) {
        float* out = (float*)outp;
        const float INV[8] = {1.f/152, 1.f/100, 1.f/76, 1.f/50, 1.f/38, 1.f/25, 1.f/19, 1.f/13};
        #pragma unroll
        for (int i = 0; i < 4; ++i)
            #pragma unroll
            for (int r4 = 0; r4 < 4; ++r4) {
                const int row = rowBase + i * 16 + rg * 4 + r4;
                if (row >= MROWS) continue;
                #pragma unroll
                for (int j = 0; j < 4; ++j) {
                    const int col = w * 64 + j * 16 + lc;
                    const int lvl = (col >> 4) & 3, xy = col & 1;
                    const float off = acc[i][j][r4] + bias[col];
                    const float ref = aux[(size_t)row * 8 + lvl * 2 + xy];
                    out[(size_t)row * 256 + col] = ref + off * INV[lvl * 2 + xy];
                }
            }
    } else if (EP == EP_ATTN) {
        if (w >= 2) return;                     // cols 128-255 are padding
        float* out = (float*)outp;
        #pragma unroll
        for (int i = 0; i < 4; ++i)
            #pragma unroll
            for (int r4 = 0; r4 < 4; ++r4) {
                const int row = rowBase + i * 16 + rg * 4 + r4;
                float v[4];
                #pragma unroll
                for (int j = 0; j < 4; ++j) v[j] = acc[i][j][r4] + bias[w * 64 + j * 16 + lc];
                float mA = fmaxf(v[0], v[1]), mB = fmaxf(v[2], v[3]);
                #pragma unroll
                for (int o = 1; o <= 8; o <<= 1) {
                    mA = fmaxf(mA, __shfl_xor(mA, o));
                    mB = fmaxf(mB, __shfl_xor(mB, o));
                }
                float e[4];
                e[0] = __expf(v[0] - mA); e[1] = __expf(v[1] - mA);
                e[2] = __expf(v[2] - mB); e[3] = __expf(v[3] - mB);
                float sA = e[0] + e[1], sB = e[2] + e[3];
                #pragma unroll
                for (int o = 1; o <= 8; o <<= 1) {
                    sA += __shfl_xor(sA, o);
                    sB += __shfl_xor(sB, o);
                }
                if (row >= MROWS) continue;
                #pragma unroll
                for (int j = 0; j < 4; ++j) {
                    const int col = w * 64 + j * 16 + lc;   // < 128
                    out[(size_t)row * 128 + col] = e[j] / (j < 2 ? sA : sB);
                }
            }
    } else {   // EP_LN: + bias + resid(fp32 aux) + LayerNorm -> bf16 out
        unsigned short* out = (unsigned short*)outp;
        #pragma unroll
        for (int i = 0; i < 4; ++i)
            #pragma unroll
            for (int r4 = 0; r4 < 4; ++r4) {
                const int row = rowBase + i * 16 + rg * 4 + r4;
                float s = 0.f, q = 0.f;
                #pragma unroll
                for (int j = 0; j < 4; ++j) {
                    const int col = w * 64 + j * 16 + lc;
                    float t = acc[i][j][r4] + bias[col];
                    if (row < MROWS) t += aux[(size_t)row * 256 + col];
                    acc[i][j][r4] = t;
                    s += t; q += t * t;
                }
                #pragma unroll
                for (int o = 1; o <= 8; o <<= 1) { s += __shfl_xor(s, o); q += __shfl_xor(q, o); }
                if (lc == 0) { ps[i * 16 + rg * 4 + r4][w] = s; pq[i * 16 + rg * 4 + r4][w] = q; }
            }
        __syncthreads();
        if (tid < 64) {
            const float s = ps[tid][0] + ps[tid][1] + ps[tid][2] + ps[tid][3];
            const float q = pq[tid][0] + pq[tid][1] + pq[tid][2] + pq[tid][3];
            const float m = s * (1.f / 256.f);
            mu_s[tid] = m;
            rs_s[tid] = rsqrtf(q * (1.f / 256.f) - m * m + 1e-5f);
        }
        __syncthreads();
        #pragma unroll
        for (int i = 0; i < 4; ++i)
            #pragma unroll
            for (int r4 = 0; r4 < 4; ++r4) {
                const int rl = i * 16 + rg * 4 + r4;
                const int row = rowBase + rl;
                if (row >= MROWS) continue;
                const float m = mu_s[rl], r = rs_s[rl];
                #pragma unroll
                for (int j = 0; j < 4; ++j) {
                    const int col = w * 64 + j * 16 + lc;
                    out[(size_t)row * 256 + col] = f2bf((acc[i][j][r4] - m) * r * g[col] + be[col]);
                }
            }
    }
}

// ---------------- FFN2: out = LN2(xb + h@W2 + b2), K=1024, h split h0/h1 ----------------
__global__ __launch_bounds__(256) void ffn2_k(
    const unsigned short* __restrict__ h0, const unsigned short* __restrict__ h1,
    const unsigned short* __restrict__ BT2,   // [256][1024]
    const float* __restrict__ bias, const unsigned short* __restrict__ xb,
    const float* __restrict__ g, const float* __restrict__ be,
    float* __restrict__ out)
{
    __shared__ __align__(16) unsigned short As[64 * 64];
    __shared__ __align__(16) unsigned short Bs[256 * 64];
    __shared__ float ps[64][4], pq[64][4];
    __shared__ float mu_s[64], rs_s[64];

    const int tid = threadIdx.x;
    const int l = tid & 63, w = tid >> 6;
    const int lc = l & 15, rg = l >> 4;
    const int rowBase = blockIdx.x * 64;

    f32x4 acc[4][4] = {};

    for (int kc = 0; kc < 16; ++kc) {
        if (kc) __syncthreads();
        const unsigned short* Ab = (kc < 8) ? h0 : h1;
        const int koff = (kc & 7) * 64;
        #pragma unroll
        for (int p = 0; p < 2; ++p) {           // stage A 64x64 from h
            const int idx = tid + p * 256;
            const int r = idx >> 3, s = idx & 7;
            const int row = rowBase + r;
            bf16x8 v = {};
            if (row < MROWS) v = *(const bf16x8*)(Ab + (size_t)row * 512 + koff + s * 8);
            *(bf16x8*)&As[r * 64 + ((s ^ (r & 7)) << 3)] = v;
        }
        #pragma unroll
        for (int p = 0; p < 8; ++p) {           // stage B 256x64
            const int idx = tid + p * 256;
            const int n = idx >> 3, s = idx & 7;
            bf16x8 v = *(const bf16x8*)(BT2 + (size_t)n * 1024 + kc * 64 + s * 8);
            *(bf16x8*)&Bs[n * 64 + ((s ^ (n & 7)) << 3)] = v;
        }
        __syncthreads();
        #pragma unroll
        for (int kk = 0; kk < 2; ++kk) {
            bf16x8 aF[4], bF[4];
            const int sl = kk * 4 + rg;
            #pragma unroll
            for (int i = 0; i < 4; ++i) {
                const int r = i * 16 + lc;
                aF[i] = *(const bf16x8*)&As[r * 64 + ((sl ^ (r & 7)) << 3)];
            }
            #pragma unroll
            for (int j = 0; j < 4; ++j) {
                const int n = w * 64 + j * 16 + lc;
                bF[j] = *(const bf16x8*)&Bs[n * 64 + ((sl ^ (n & 7)) << 3)];
            }
            #pragma unroll
            for (int i = 0; i < 4; ++i)
                #pragma unroll
                for (int j = 0; j < 4; ++j)
                    acc[i][j] = __builtin_amdgcn_mfma_f32_16x16x32_bf16(aF[i], bF[j], acc[i][j], 0, 0, 0);
        }
    }

    // epilogue: + b2 + resid(xb bf16) + LN2 -> fp32
    #pragma unroll
    for (int i = 0; i < 4; ++i)
        #pragma unroll
        for (int r4 = 0; r4 < 4; ++r4) {
            const int row = rowBase + i * 16 + rg * 4 + r4;
            float s = 0.f, q = 0.f;
            #pragma unroll
            for (int j = 0; j < 4; ++j) {
                const int col = w * 64 + j * 16 + lc;
                float t = acc[i][j][r4] + bias[col];
                if (row < MROWS) t += bf2f(xb[(size_t)row * 256 + col]);
                acc[i][j][r4] = t;
                s += t; q += t * t;
            }
            #pragma unroll
            for (int o = 1; o <= 8; o <<= 1) { s += __shfl_xor(s, o); q += __shfl_xor(q, o); }
            if (lc == 0) { ps[i * 16 + rg * 4 + r4][w] = s; pq[i * 16 + rg * 4 + r4][w] = q; }
        }
    __syncthreads();
    if (tid < 64) {
        const float s = ps[tid][0] + ps[tid][1] + ps[tid][2] + ps[tid][3];
        const float q = pq[tid][0] + pq[tid][1] + pq[tid][2] + pq[tid][3];
        const float m = s * (1.f / 256.f);
        mu_s[tid] = m;
        rs_s[tid] = rsqrtf(q * (1.f / 256.f) - m * m + 1e-5f);
    }
    __syncthreads();
    #pragma unroll
    for (int i = 0; i < 4; ++i)
        #pragma unroll
        for (int r4 = 0; r4 < 4; ++r4) {
            const int rl = i * 16 + rg * 4 + r4;
            const int row = rowBase + rl;
            if (row >= MROWS) continue;
            const float m = mu_s[rl], r = rs_s[rl];
            #pragma unroll
            for (int j = 0; j < 4; ++j) {
                const int col = w * 64 + j * 16 + lc;
                out[(size_t)row * 256 + col] = (acc[i][j][r4] - m) * r * g[col] + be[col];
            }
        }
}

// ---------------- deformable sampling v3: packed-fp32 math, 16B loads ----------------
// Block 256 = 8 queries x 32 channel-octets. Phase 1: per-tap (byteoff, w) into LDS,
// clamped+branchless. Phase 2: uint4 loads, bf16 pair-unpack, v_pk_fma_f32.
#define QB2 8
__global__ __launch_bounds__(256) void sample_k(
    const unsigned short* __restrict__ value, const float* __restrict__ loc_i,
    const float* __restrict__ attn_i, unsigned short* __restrict__ samp_o)
{
    constexpr int LVL_H[4] = {100, 50, 25, 13};
    constexpr int LVL_W[4] = {152, 76, 38, 19};
    constexpr int LVL_S[4] = {0, 15200, 19000, 19950};
    const int tid = threadIdx.x;

    // bijective XCD-chunked swizzle (m204)
    const int nwg = gridDim.x;
    const int bid = blockIdx.x;
    const int xcd = bid & 7, lid = bid >> 3;
    const int qq = nwg >> 3, rr = nwg & 7;
    const int sw = (xcd < rr ? xcd * (qq + 1) : rr * (qq + 1) + (xcd - rr) * qq) + lid;
    const int rowBase = sw * QB2;

    __shared__ int2 sT[QB2][4][128];   // [query][neighbor][tap] = (byte offset, weight)

    // ---- phase 1: 1024 taps, 4 per thread ----
    #pragma unroll
    for (int it = 0; it < 4; ++it) {
        const int item = tid + it * 256;
        const int qs = item >> 7;
        const int t  = item & 127;          // m*32 + l*8 + p
        const int row = rowBase + qs;
        if (row < MROWS) {
            const int lv = (t >> 3) & 3;
            const int n = (row >= LQ) ? 1 : 0;
            const int H = LVL_H[lv], W = LVL_W[lv];
            const float lx = loc_i[(size_t)row * 256 + t * 2 + 0];
            const float ly = loc_i[(size_t)row * 256 + t * 2 + 1];
            const float a  = attn_i[(size_t)row * 128 + t];
            const float x = lx * (float)W - 0.5f;
            const float y = ly * (float)H - 0.5f;
            const float x0f = floorf(x), y0f = floorf(y);
            const float wx = x - x0f, wy = y - y0f;
            const int x0 = (int)x0f, y0 = (int)y0f;
            const int base = n * LQ + LVL_S[lv];
            #pragma unroll
            for (int nb = 0; nb < 4; ++nb) {
                const int dx = nb & 1, dy = nb >> 1;
                const int xi = x0 + dx, yi = y0 + dy;
                const bool valid = (xi >= 0) & (xi < W) & (yi >= 0) & (yi < H);
                const float wgt = (dx ? wx : 1.f - wx) * (dy ? wy : 1.f - wy) * a;
                const int xc = min(max(xi, 0), W - 1);
                const int yc = min(max(yi, 0), H - 1);
                const int off = (base + yc * W + xc) << 9;   // *512 bytes per row
                sT[qs][nb][t] = make_int2(off, valid ? __float_as_int(wgt) : 0);
            }
        }
    }
    __syncthreads();

    // ---- phase 2: thread = (qs, c8); channels [c8*8, c8*8+8) ----
    const int qs = tid >> 5;
    const int c8 = tid & 31;
    const int row = rowBase + qs;
    if (row >= MROWS) return;
    const int m = c8 >> 3;                       // head
    const char* vb = (const char*)value + c8 * 16;
    const int2* tp = &sT[qs][0][m * 32];

    f32x2 a0 = {0.f, 0.f}, a1 = {0.f, 0.f}, a2 = {0.f, 0.f}, a3 = {0.f, 0.f};
    #pragma unroll 4
    for (int i = 0; i < 128; ++i) {
        const int t0 = i >> 2, nb = i & 3;
        const int2 ow = tp[nb * 128 + t0];
        const float w = __int_as_float(ow.y);
        const uint4 u = *(const uint4*)(vb + ow.x);
        const f32x2 wv = {w, w};
        f32x2 p;
        p.x = __uint_as_float(u.x << 16); p.y = __uint_as_float(u.x & 0xffff0000u);
        a0 = __builtin_elementwise_fma(p, wv, a0);
        p.x = __uint_as_float(u.y << 16); p.y = __uint_as_float(u.y & 0xffff0000u);
        a1 = __builtin_elementwise_fma(p, wv, a1);
        p.x = __uint_as_float(u.z << 16); p.y = __uint_as_float(u.z & 0xffff0000u);
        a2 = __builtin_elementwise_fma(p, wv, a2);
        p.x = __uint_as_float(u.w << 16); p.y = __uint_as_float(u.w & 0xffff0000u);
        a3 = __builtin_elementwise_fma(p, wv, a3);
    }
    uint4 o;
    o.x = (unsigned)f2bf(a0.x) | ((unsigned)f2bf(a0.y) << 16);
    o.y = (unsigned)f2bf(a1.x) | ((unsigned)f2bf(a1.y) << 16);
    o.z = (unsigned)f2bf(a2.x) | ((unsigned)f2bf(a2.y) << 16);
    o.w = (unsigned)f2bf(a3.x) | ((unsigned)f2bf(a3.y) << 16);
    *(uint4*)(samp_o + (size_t)row * 256 + c8 * 8) = o;
}

extern "C" void kernel_launch(void* const* d_in, const int* in_sizes, int n_in,
                              void* d_out, int out_size, void* d_ws, size_t ws_size,
                              hipStream_t stream)
{
    const float* src_feat = (const float*)d_in[0];
    const float* refpts   = (const float*)d_in[1];
    const float* key_feat = (const float*)d_in[2];
    const float* W_off  = (const float*)d_in[5];
    const float* b_off  = (const float*)d_in[6];
    const float* W_attn = (const float*)d_in[7];
    const float* b_attn = (const float*)d_in[8];
    const float* W_val  = (const float*)d_in[9];
    const float* b_val  = (const float*)d_in[10];
    const float* W_out  = (const float*)d_in[11];
    const float* b_out  = (const float*)d_in[12];
    const float* W1  = (const float*)d_in[13];
    const float* b1  = (const float*)d_in[14];
    const float* W2  = (const float*)d_in[15];
    const float* b2  = (const float*)d_in[16];
    const float* g1  = (const float*)d_in[17];
    const float* be1 = (const float*)d_in[18];
    const float* g2  = (const float*)d_in[19];
    const float* be2 = (const float*)d_in[20];

    float* out = (float*)d_out;
    float* x_out    = out;                           // (M,256) fp32
    float* loc_out  = out + MR256;                   // (M,256) fp32
    float* attn_out = out + 2 * MR256;               // (M,128) fp32

    char* ws = (char*)d_ws;
    unsigned short* BTv   = (unsigned short*)(ws + 0);
    unsigned short* BTo   = (unsigned short*)(ws + 131072);
    unsigned short* BTa   = (unsigned short*)(ws + 262144);
    unsigned short* BTu   = (unsigned short*)(ws + 393216);
    unsigned short* BT1   = (unsigned short*)(ws + 524288);
    unsigned short* BT2   = (unsigned short*)(ws + 1048576);
    float*          battn = (float*)(ws + 1572864);
    unsigned short* value = (unsigned short*)(ws + 2097152);
    unsigned short* samp  = (unsigned short*)(ws + 2097152 + MR256 * 2);
    unsigned short* xb    = (unsigned short*)(ws + 2097152 + MR256 * 4);
    unsigned short* h0    = value;                       // [M][512] bf16 overlays value+samp
    unsigned short* h1    = (unsigned short*)x_out;      // [M][512] bf16 overlays x_out

    const int RB = (MROWS + 63) / 64;   // 632

    prep_w_k<<<512, 256, 0, stream>>>(W_val, W_off, W_attn, W_out, W1, W2, b_attn,
                                      BTv, BTo, BTa, BTu, BT1, BT2, battn);
    // value = key@Wv+bv (bf16)
    gemm_k<EP_VAL, true><<<dim3(RB, 1), 256, 0, stream>>>(key_feat, BTv, b_val, nullptr, nullptr, nullptr, value, nullptr);
    // loc = ref + (src@Wo+bo)/norm  -> d_out
    gemm_k<EP_LOC, true><<<dim3(RB, 1), 256, 0, stream>>>(src_feat, BTo, b_off, refpts, nullptr, nullptr, loc_out, nullptr);
    // attn = softmax(src@Wa+ba) -> d_out
    gemm_k<EP_ATTN, true><<<dim3(RB, 1), 256, 0, stream>>>(src_feat, BTa, battn, nullptr, nullptr, nullptr, attn_out, nullptr);
    // deformable sampling -> bf16 samp
    sample_k<<<(MROWS + QB2 - 1) / QB2, 256, 0, stream>>>(value, loc_out, attn_out, samp);
    // x = LN1(src + samp@Wu+bu) -> bf16 xb
    gemm_k<EP_LN, false><<<dim3(RB, 1), 256, 0, stream>>>(samp, BTu, b_out, src_feat, g1, be1, xb, nullptr);
    // h = relu(x@W1+b1) -> bf16, split h0 (cols 0-511) / h1 (cols 512-1023)
    gemm_k<EP_FFN1, false><<<dim3(RB, 4), 256, 0, stream>>>(xb, BT1, b1, nullptr, nullptr, nullptr, h0, h1);
    // x2 = LN2(x + h@W2+b2) -> fp32 d_out
    ffn2_k<<<dim3(RB, 1), 256, 0, stream>>>(h0, h1, BT2, b2, xb, g2, be2, x_out);
}